// Round 1
// baseline (2095.987 us; speedup 1.0000x reference)
//
#include <hip/hip_runtime.h>
#include <cstdint>
#include <cstddef>

typedef _Float16 f16;
typedef _Float16 f16x8 __attribute__((ext_vector_type(8)));
typedef _Float16 f16x2 __attribute__((ext_vector_type(2)));
typedef float    f32x4 __attribute__((ext_vector_type(4)));

#define DEV static __device__ __forceinline__

constexpr int TOUT = 31;
constexpr int VOC  = 34004;
constexpr int VOCP = 34048;

// ---------------- ws layout (bytes) ----------------
constexpr size_t OFF_SYNC  = 0;                                         // 256
constexpr size_t OFF_MEM16 = 256;                                       // [3840][512] f16
constexpr size_t OFF_WMSWZ = OFF_MEM16 + (size_t)3840*512*2;            // [16][512][32] f16
constexpr size_t OFF_KEYS  = OFF_WMSWZ + (size_t)16*512*32*2;           // [3840][512] f32
constexpr size_t OFF_EMBA  = OFF_KEYS  + (size_t)3840*512*4;            // [1984][320] f16
constexpr size_t OFF_WKTOP = OFF_EMBA  + (size_t)1984*320*2;            // [10][2048][32] f16 (perm)
constexpr size_t OFF_EMBW  = OFF_WKTOP + (size_t)10*2048*32*2;          // [1984][2048] f32 (perm cols)
constexpr size_t OFF_WA16  = OFF_EMBW  + (size_t)1984*2048*4;           // [1024][512] f16 rowmajor
constexpr size_t OFF_WKATT = OFF_WA16  + (size_t)1024*512*2;            // [16][2048][32] f16 (perm)
constexpr size_t OFF_WCA   = OFF_WKATT + (size_t)16*2048*32*2;          // [1024][2048] f32 (perm cols)
constexpr size_t OFF_WSTAR = OFF_WCA   + (size_t)1024*2048*4;           // [32][2048][32] f16 (perm)
constexpr size_t OFF_UK16  = OFF_WSTAR + (size_t)32*2048*32*2;          // [16][2048][32] f16 (perm)
constexpr size_t OFF_WQT   = OFF_UK16  + (size_t)16*2048*32*2;          // [512 j][512 u] f16 (transposed Wq)
constexpr size_t OFF_WASWZ = OFF_WQT   + (size_t)512*512*2;             // [32][512][32] f16
constexpr size_t OFF_H016  = OFF_WASWZ + (size_t)32*512*32*2;           // [64][512] f16
constexpr size_t OFF_C32   = OFF_H016  + (size_t)64*512*2;              // [64][512] f32
constexpr size_t OFF_YALL  = OFF_C32   + (size_t)64*512*4;              // [31][64][1024] f16
constexpr size_t OFF_ZP    = OFF_YALL  + (size_t)31*64*1024*2;          // [4][64][2048] f32
constexpr size_t OFF_ATT16 = OFF_ZP    + (size_t)4*64*2048*4;           // [1984][512] f16
constexpr size_t OFF_BKP   = OFF_ATT16 + (size_t)1984*512*2;            // [2048] f32 (perm bk)
constexpr size_t OFF_WFC   = OFF_BKP   + (size_t)2048*4;                // [16][34048][32] f16

// ---------------- helpers ----------------
DEV void gload16(const void* src, void* ldsbase /* wave-uniform */) {
  __builtin_amdgcn_global_load_lds(
      (const __attribute__((address_space(1))) unsigned int*)src,
      (__attribute__((address_space(3))) unsigned int*)ldsbase, 16, 0, 0);
}

DEV float sigm(float x)      { return 1.f / (1.f + expf(-x)); }
DEV float tanh_fast(float x) { float e = __expf(2.f*x); return 1.f - 2.f/(e+1.f); }

// ---------------- prep: elementwise conversions ----------------
__global__ void prep_elem(char* ws, const int* dec, const float* h0,
                          const float* memory, const float* embt,
                          const float* Wq, const float* Wa, const float* bk)
{
  f16* mem16 = (f16*)(ws+OFF_MEM16);
  f16* embA  = (f16*)(ws+OFF_EMBA);
  f16* wa16  = (f16*)(ws+OFF_WA16);
  f16* wqT   = (f16*)(ws+OFF_WQT);
  f16* h016  = (f16*)(ws+OFF_H016);
  float* bkp = (float*)(ws+OFF_BKP);
  constexpr int E0=1966080, E1=E0+634880, E2=E1+524288, E3=E2+262144, E4=E3+32768, E5=E4+2048;
  for (int i = blockIdx.x*256 + threadIdx.x; i < E5; i += gridDim.x*256) {
    if (i < E0) { mem16[i] = (f16)memory[i]; }
    else if (i < E1) { int j=i-E0; int r=j/320, k=j-r*320; int t=r>>6, b=r&63;
      int tok = dec[b*TOUT+t];
      embA[j] = (k<300) ? (f16)embt[(size_t)tok*300+k] : (f16)0.f; }
    else if (i < E2) { int j=i-E1; wa16[j] = (f16)Wa[j]; }
    else if (i < E3) { int j=i-E2; int jj=j>>9, u=j&511; wqT[j] = (f16)Wq[(size_t)u*512+jj]; }
    else if (i < E4) { int j=i-E3; h016[j] = (f16)h0[j]; }
    else { int j=i-E4; bkp[j] = bk[(j>>2) + (j&3)*512]; }
  }
}

// ---------------- prep: swizzled B-layouts [K/32][N][32] ----------------
__global__ void prep_swz(char* ws, const float* Wm, const float* Wk, const float* Uk, const float* Wa)
{
  int tg = blockIdx.x*256 + threadIdx.x;
  constexpr int S0=8192, S1=S0+20480, S2=S1+32768, S3=S2+32768, S4=S3+16384;
  if (tg >= S4) return;
  f16 buf[32];
  f16* dst;
  if (tg < S0) {                       // Wm -> [16][512][32]
    int kt=tg>>9, n=tg&511;
    #pragma unroll
    for (int kk=0;kk<32;kk++) buf[kk] = (f16)Wm[(size_t)(kt*32+kk)*512 + n];
    dst = (f16*)(ws+OFF_WMSWZ) + (size_t)tg*32;
  } else if (tg < S1) {                // Wk rows 0..299 (pad->320), perm cols -> [10][2048][32]
    int j=tg-S0; int kt=j>>11, np=j&2047; int col=(np>>2)+(np&3)*512;
    #pragma unroll
    for (int kk=0;kk<32;kk++){ int k=kt*32+kk;
      buf[kk] = (k<300) ? (f16)Wk[(size_t)k*2048+col] : (f16)0.f; }
    dst = (f16*)(ws+OFF_WKTOP) + (size_t)j*32;
  } else if (tg < S2) {                // Wk rows 300..811, perm -> [16][2048][32]
    int j=tg-S1; int kt=j>>11, np=j&2047; int col=(np>>2)+(np&3)*512;
    #pragma unroll
    for (int kk=0;kk<32;kk++) buf[kk] = (f16)Wk[(size_t)(300+kt*32+kk)*2048+col];
    dst = (f16*)(ws+OFF_WKATT) + (size_t)j*32;
  } else if (tg < S3) {                // Uk, perm -> [16][2048][32]
    int j=tg-S2; int kt=j>>11, np=j&2047; int col=(np>>2)+(np&3)*512;
    #pragma unroll
    for (int kk=0;kk<32;kk++) buf[kk] = (f16)Uk[(size_t)(kt*32+kk)*2048+col];
    dst = (f16*)(ws+OFF_UK16) + (size_t)j*32;
  } else {                             // Wa -> [32][512][32]
    int j=tg-S3; int kt=j>>9, n=j&511;
    #pragma unroll
    for (int kk=0;kk<32;kk++) buf[kk] = (f16)Wa[(size_t)(kt*32+kk)*512 + n];
    dst = (f16*)(ws+OFF_WASWZ) + (size_t)j*32;
  }
  f16x8* d8 = (f16x8*)dst; f16x8* s8 = (f16x8*)buf;
  d8[0]=s8[0]; d8[1]=s8[1]; d8[2]=s8[2]; d8[3]=s8[3];
}

// ---------------- prep: Wfc -> [16][34048][32] f16 ----------------
__global__ void prep_wfc(char* ws, const float* Wfc)
{
  int n  = blockIdx.x*256 + threadIdx.x;   // 0..34047
  int kt = blockIdx.y;                      // 0..15
  f16 buf[32];
  #pragma unroll
  for (int kk=0;kk<32;kk++)
    buf[kk] = (n < VOC) ? (f16)Wfc[(size_t)(kt*32+kk)*VOC + n] : (f16)0.f;
  f16* dst = (f16*)(ws+OFF_WFC) + ((size_t)kt*VOCP + n)*32;
  f16x8* d8 = (f16x8*)dst; f16x8* s8 = (f16x8*)buf;
  d8[0]=s8[0]; d8[1]=s8[1]; d8[2]=s8[2]; d8[3]=s8[3];
}

// ---------------- build W* = Wca + [Uk;0] -> [32][2048][32] (perm) ----------------
__global__ void build_wstar(char* ws, const float* Uk)
{
  int tg = blockIdx.x*256 + threadIdx.x;   // 65536
  int kt = tg>>11, np = tg&2047;
  int col = (np>>2)+(np&3)*512;
  const float* wca = (const float*)(ws+OFF_WCA);
  f16 buf[32];
  #pragma unroll
  for (int kk=0;kk<32;kk++){
    int k = kt*32+kk;
    float v = wca[(size_t)k*2048 + np];
    if (k < 512) v += Uk[(size_t)k*2048 + col];
    buf[kk] = (f16)v;
  }
  f16* dst = (f16*)(ws+OFF_WSTAR) + (size_t)tg*32;
  f16x8* d8 = (f16x8*)dst; f16x8* s8 = (f16x8*)buf;
  d8[0]=s8[0]; d8[1]=s8[1]; d8[2]=s8[2]; d8[3]=s8[3];
}

// ---------------- generic fp16 MFMA GEMM ----------------
// C[M,N] = A[M,K](rowmajor f16) @ Bswz[K/32][Np][32]
// MODE 0: f32 out rowmajor (ld=Np) + optional bias[n]
// MODE 1: f16 out rowmajor (ld=Np)
// MODE 2: scatter out[(b*31+t)*VOC + n] = v + bias[n], m = t*64+b, mask m<Mreal,n<Nreal
template<int BM, int BN, int WR, int WC, int MODE>
__global__ __launch_bounds__(WR*WC*64, 1)
void gemm16(const f16* __restrict__ A, int lda,
            const f16* __restrict__ Bs, int Np,
            void* __restrict__ C, const float* __restrict__ bias,
            int M, int K, int Mreal, int Nreal)
{
  constexpr int NT  = WR*WC*64;
  constexpr int WTM = BM/WR, WTN = BN/WC, AM = WTM/16, AN = WTN/16;
  constexpr int NLA = BM*64/(NT*16), NLB = BN*64/(NT*16);
  __shared__ __align__(16) f16 sA[BM*32];
  __shared__ __align__(16) f16 sB[BN*32];
  const int tid = threadIdx.x, wave = tid>>6, lane = tid&63;
  const int lg = lane>>4, lr = lane&15;
  const int m0 = blockIdx.y*BM, n0 = blockIdx.x*BN;
  const int wm = (wave/WC)*WTM, wn = (wave%WC)*WTN;

  f32x4 acc[AM][AN] = {};

  int aoff[AM], boff[AN];
  #pragma unroll
  for (int i=0;i<AM;i++){ int row = wm+i*16+lr; aoff[i] = row*64 + (((lg + (row>>1))&3)<<4); }
  #pragma unroll
  for (int i=0;i<AN;i++){ int row = wn+i*16+lr; boff[i] = row*64 + (((lg + (row>>1))&3)<<4); }

  const int ksteps = K/32;
  for (int ks=0; ks<ksteps; ks++){
    const int k0 = ks*32;
    __syncthreads();
    #pragma unroll
    for (int i=0;i<NLA;i++){
      int p = i*NT + tid;
      int row = p>>2; int g = ((p&3) - (row>>1)) & 3;
      int gm = m0+row; if (gm > Mreal-1) gm = Mreal-1;
      gload16(A + (size_t)gm*lda + k0 + g*8, (char*)sA + (i*NT + wave*64)*16);
    }
    #pragma unroll
    for (int i=0;i<NLB;i++){
      int p = i*NT + tid;
      int row = p>>2; int g = ((p&3) - (row>>1)) & 3;
      gload16(Bs + ((size_t)(k0>>5)*Np + (n0+row))*32 + g*8, (char*)sB + (i*NT + wave*64)*16);
    }
    __syncthreads();
    f16x8 af[AM], bf[AN];
    #pragma unroll
    for (int i=0;i<AM;i++) af[i] = *(const f16x8*)((const char*)sA + aoff[i]);
    #pragma unroll
    for (int i=0;i<AN;i++) bf[i] = *(const f16x8*)((const char*)sB + boff[i]);
    #pragma unroll
    for (int i=0;i<AM;i++)
      #pragma unroll
      for (int j=0;j<AN;j++)
        acc[i][j] = __builtin_amdgcn_mfma_f32_16x16x32_f16(af[i], bf[j], acc[i][j], 0,0,0);
  }

  #pragma unroll
  for (int i=0;i<AM;i++)
    #pragma unroll
    for (int j=0;j<AN;j++){
      int n = n0 + wn + j*16 + lr;
      if (MODE == 2 && n >= Nreal) continue;
      float bb = 0.f;
      if (MODE != 1 && bias) bb = bias[n];
      #pragma unroll
      for (int r=0;r<4;r++){
        int m = m0 + wm + i*16 + lg*4 + r;
        if (m >= Mreal) continue;
        float v = acc[i][j][r] + bb;
        if (MODE == 0)      ((float*)C)[(size_t)m*Np + n] = v;
        else if (MODE == 1) ((f16*)C)[(size_t)m*Np + n] = (f16)v;
        else { int t = m>>6, b = m&63; ((float*)C)[((size_t)(b*TOUT+t))*VOC + n] = v; }
      }
    }
}

// ---------------- grid barrier ----------------
DEV void gbar(int* cnt, int* gen, int nb)
{
  __syncthreads();
  if (threadIdx.x == 0) {
    __threadfence();  // release: flush local L2 so other XCDs can see our data
    int g = __hip_atomic_load(gen, __ATOMIC_RELAXED, __HIP_MEMORY_SCOPE_AGENT);
    int a = __hip_atomic_fetch_add(cnt, 1, __ATOMIC_ACQ_REL, __HIP_MEMORY_SCOPE_AGENT) + 1;
    if (a == nb) {
      __hip_atomic_store(cnt, 0,   __ATOMIC_RELAXED, __HIP_MEMORY_SCOPE_AGENT);
      __hip_atomic_store(gen, g+1, __ATOMIC_RELEASE, __HIP_MEMORY_SCOPE_AGENT);
    } else {
      while (__hip_atomic_load(gen, __ATOMIC_RELAXED, __HIP_MEMORY_SCOPE_AGENT) == g)
        __builtin_amdgcn_s_sleep(8);
    }
    __threadfence();  // acquire: invalidate stale lines before reading remote data
  }
  __syncthreads();
}

// ---------------- persistent recurrence kernel: 128 blocks x 512 threads ----------------
__global__ __launch_bounds__(512, 1)
void recur(char* ws, const float* __restrict__ c0, const float* __restrict__ memory,
           const float* __restrict__ v_att)
{
  f16*  y_all = (f16*)(ws+OFF_YALL);
  const f16* h016 = (const f16*)(ws+OFF_H016);
  const f16* wstar = (const f16*)(ws+OFF_WSTAR);
  const f16* uk16  = (const f16*)(ws+OFF_UK16);
  const f16* wqT   = (const f16*)(ws+OFF_WQT);
  float* zp   = (float*)(ws+OFF_ZP);
  float* c32  = (float*)(ws+OFF_C32);
  const float* embw = (const float*)(ws+OFF_EMBW);
  const float* keys = (const float*)(ws+OFF_KEYS);
  int* cnt = (int*)(ws+OFF_SYNC);
  int* gen = cnt + 1;

  const int blk = blockIdx.x;                 // 0..127
  const int tid = threadIdx.x;                // 0..511
  const int wave = tid>>6, lane = tid&63, lg = lane>>4, lr = lane&15;

  __shared__ __align__(16) f16 sA[64*32];
  __shared__ __align__(16) f16 sB[64*32];
  __shared__ __align__(16) float h_lds[512];
  __shared__ __align__(16) f16   h16_lds[512];
  __shared__ __align__(16) float q_lds[512];
  __shared__ __align__(16) float sc_lds[64];
  __shared__ __align__(16) float v_lds[512];

  if (blk < 64) v_lds[tid] = v_att[tid];

  // P1 geometry (fixed per block)
  const int kz = blk & 3, nc = blk >> 2;      // k-split 4, 32 n-chunks
  const int n0 = nc*64;
  const int wmg = (wave>>2)*32, wng = (wave&3)*16;
  int aoff[2], boff;
  #pragma unroll
  for (int i=0;i<2;i++){ int row = wmg+i*16+lr; aoff[i] = row*64 + (((lg + (row>>1))&3)<<4); }
  { int row = wng+lr;   boff   = row*64 + (((lg + (row>>1))&3)<<4); }

  for (int t=0; t<TOUT; t++){
    // ---------- P1: zp[kz][b][n'] = (y(t-1) @ W*) k-slice ----------
    const f16* Aptr; int lda, kbase, ksteps; const f16* Bsw;
    if (t == 0) { Aptr = h016; lda = 512;  kbase = kz*128; ksteps = 4; Bsw = uk16; }
    else { Aptr = y_all + (size_t)(t-1)*64*1024; lda = 1024; kbase = kz*256; ksteps = 8; Bsw = wstar; }

    f32x4 acc0 = {}, acc1 = {};
    for (int ks=0; ks<ksteps; ks++){
      const int k0 = kbase + ks*32;
      __syncthreads();
      if (wave < 4) {            // stage A tile [64][32]
        int p = (wave&3)*64 + lane;
        int row = p>>2; int g = ((p&3) - (row>>1)) & 3;
        gload16(Aptr + (size_t)row*lda + k0 + g*8, (char*)sA + (wave&3)*1024);
      } else {                   // stage B tile [64 n'][32]
        int p = (wave&3)*64 + lane;
        int row = p>>2; int g = ((p&3) - (row>>1)) & 3;
        gload16(Bsw + ((size_t)(k0>>5)*2048 + n0 + row)*32 + g*8, (char*)sB + (wave&3)*1024);
      }
      __syncthreads();
      f16x8 a0 = *(const f16x8*)((const char*)sA + aoff[0]);
      f16x8 a1 = *(const f16x8*)((const char*)sA + aoff[1]);
      f16x8 b0 = *(const f16x8*)((const char*)sB + boff);
      acc0 = __builtin_amdgcn_mfma_f32_16x16x32_f16(a0, b0, acc0, 0,0,0);
      acc1 = __builtin_amdgcn_mfma_f32_16x16x32_f16(a1, b0, acc1, 0,0,0);
    }
    {
      int np = n0 + wng + lr;
      #pragma unroll
      for (int r=0;r<4;r++){
        int b0r = wmg + 0*16 + lg*4 + r;
        int b1r = wmg + 1*16 + lg*4 + r;
        zp[((size_t)(kz*64 + b0r))*2048 + np] = acc0[r];
        zp[((size_t)(kz*64 + b1r))*2048 + np] = acc1[r];
      }
    }
    gbar(cnt, gen, 128);

    // ---------- P2: per-batch gates + attention ----------
    if (blk < 64) {
      const int b = blk;
      // gates: u = tid
      {
        const int u = tid;
        f32x4 z = *(const f32x4*)(zp + ((size_t)(0*64+b))*2048 + u*4);
        f32x4 z1 = *(const f32x4*)(zp + ((size_t)(1*64+b))*2048 + u*4);
        f32x4 z2 = *(const f32x4*)(zp + ((size_t)(2*64+b))*2048 + u*4);
        f32x4 z3 = *(const f32x4*)(zp + ((size_t)(3*64+b))*2048 + u*4);
        f32x4 e  = *(const f32x4*)(embw + ((size_t)(t*64+b))*2048 + u*4);
        float zi = z[0]+z1[0]+z2[0]+z3[0]+e[0];
        float zf = z[1]+z1[1]+z2[1]+z3[1]+e[1];
        float zg = z[2]+z1[2]+z2[2]+z3[2]+e[2];
        float zo = z[3]+z1[3]+z2[3]+z3[3]+e[3];
        float ig = sigm(zi), fg = sigm(zf), gg = tanhf(zg), og = sigm(zo);
        float cold = (t==0) ? c0[b*512+u] : c32[b*512+u];
        float cn = fg*cold + ig*gg;
        c32[b*512+u] = cn;
        float h = og * tanhf(cn);
        h_lds[u] = h;
        h16_lds[u] = (f16)h;
        y_all[((size_t)t*64 + b)*1024 + u] = (f16)h;
      }
      __syncthreads();
      // q[j] = h . Wq[:,j]  (WqT rows contiguous in u, fdot2)
      {
        const int j = tid;
        const f16* wrow = wqT + (size_t)j*512;
        float acc = 0.f;
        #pragma unroll 8
        for (int u2=0; u2<256; u2++){
          f16x2 w2 = *(const f16x2*)(wrow + u2*2);
          f16x2 h2 = *(const f16x2*)(h16_lds + u2*2);
          acc = __builtin_amdgcn_fdot2(h2, w2, acc, false);
        }
        q_lds[j] = acc;
      }
      __syncthreads();
      // scores: one wave per i
      for (int i = wave; i < 60; i += 8){
        const float* krow = keys + ((size_t)(b*60+i))*512;
        float p = 0.f;
        #pragma unroll
        for (int s=0;s<8;s++){
          int u = lane + s*64;
          p += tanh_fast(krow[u] + q_lds[u]) * v_lds[u];
        }
        #pragma unroll
        for (int m=32;m;m>>=1) p += __shfl_xor(p, m, 64);
        if (lane == 0) sc_lds[i] = p;
      }
      __syncthreads();
      if (wave == 0){
        float s = (lane < 60) ? sc_lds[lane] : -1e30f;
        float mx = s;
        #pragma unroll
        for (int m=32;m;m>>=1) mx = fmaxf(mx, __shfl_xor(mx, m, 64));
        float ev = (lane < 60) ? __expf(s - mx) : 0.f;
        float sum = ev;
        #pragma unroll
        for (int m=32;m;m>>=1) sum += __shfl_xor(sum, m, 64);
        if (lane < 60) sc_lds[lane] = ev / sum;
      }
      __syncthreads();
      // ctx[d] = sum_i align[i]*memory[b,i,d]
      {
        const int d = tid;
        float cx = 0.f;
        const float* mrow = memory + ((size_t)b*60)*512 + d;
        #pragma unroll 4
        for (int i=0;i<60;i++) cx += sc_lds[i] * mrow[(size_t)i*512];
        y_all[((size_t)t*64 + b)*1024 + 512 + d] = (f16)cx;
      }
    }
    gbar(cnt, gen, 128);
  }
}

// ---------------- host ----------------
extern "C" void kernel_launch(void* const* d_in, const int* in_sizes, int n_in,
                              void* d_out, int out_size, void* d_ws, size_t ws_size,
                              hipStream_t stream)
{
  const int*   dec  = (const int*)  d_in[0];
  const float* h0   = (const float*)d_in[1];
  const float* c0   = (const float*)d_in[2];
  const float* mem  = (const float*)d_in[3];
  const float* embt = (const float*)d_in[4];
  const float* Wk   = (const float*)d_in[5];
  const float* Uk   = (const float*)d_in[6];
  const float* bk   = (const float*)d_in[7];
  const float* Wm   = (const float*)d_in[8];
  const float* Wq   = (const float*)d_in[9];
  const float* va   = (const float*)d_in[10];
  const float* Wa   = (const float*)d_in[11];
  const float* Wfc  = (const float*)d_in[12];
  const float* bfc  = (const float*)d_in[13];
  char* ws = (char*)d_ws;

  hipMemsetAsync(ws + OFF_SYNC, 0, 256, stream);

  prep_elem<<<4096, 256, 0, stream>>>(ws, dec, h0, mem, embt, Wq, Wa, bk);
  prep_swz <<<432, 256, 0, stream>>>(ws, Wm, Wk, Uk, Wa);
  prep_wfc <<<dim3(133,16), 256, 0, stream>>>(ws, Wfc);

  // keys = memory @ Wm : [3840,512] f32
  gemm16<128,64,2,2,0><<<dim3(8,30), 256, 0, stream>>>(
      (const f16*)(ws+OFF_MEM16), 512, (const f16*)(ws+OFF_WMSWZ), 512,
      ws+OFF_KEYS, nullptr, 3840, 512, 3840, 512);
  // embW = embA @ WkTop + bk_perm : [1984,2048] f32 (perm cols)
  gemm16<128,64,2,2,0><<<dim3(32,16), 256, 0, stream>>>(
      (const f16*)(ws+OFF_EMBA), 320, (const f16*)(ws+OFF_WKTOP), 2048,
      ws+OFF_EMBW, (const float*)(ws+OFF_BKP), 1984, 320, 1984, 2048);
  // Wca = Wa @ WkAttn : [1024,2048] f32 (perm cols)
  gemm16<128,64,2,2,0><<<dim3(32,8), 256, 0, stream>>>(
      (const f16*)(ws+OFF_WA16), 512, (const f16*)(ws+OFF_WKATT), 2048,
      ws+OFF_WCA, nullptr, 1024, 512, 1024, 2048);
  build_wstar<<<256, 256, 0, stream>>>(ws, Uk);

  recur<<<128, 512, 0, stream>>>(ws, c0, mem, va);

  // attn_all = Y @ Wa : [1984,512] f16
  gemm16<128,64,2,2,1><<<dim3(8,16), 256, 0, stream>>>(
      (const f16*)(ws+OFF_YALL), 1024, (const f16*)(ws+OFF_WASWZ), 512,
      ws+OFF_ATT16, nullptr, 1984, 1024, 1984, 512);
  // logits = attn_all @ Wfc + bfc -> d_out [b][t][vocab]
  gemm16<128,256,2,4,2><<<dim3(133,16), 512, 0, stream>>>(
      (const f16*)(ws+OFF_ATT16), 512, (const f16*)(ws+OFF_WFC), VOCP,
      d_out, bfc, 1984, 512, 1984, VOC);
}

// Round 2
// 1296.569 us; speedup vs baseline: 1.6166x; 1.6166x over previous
//
#include <hip/hip_runtime.h>
#include <cstdint>
#include <cstddef>

typedef _Float16 f16;
typedef _Float16 f16x8 __attribute__((ext_vector_type(8)));
typedef _Float16 f16x2 __attribute__((ext_vector_type(2)));
typedef float    f32x4 __attribute__((ext_vector_type(4)));

#define DEV static __device__ __forceinline__

constexpr int TOUT = 31;
constexpr int VOC  = 34004;
constexpr int VOCP = 34048;

// ---------------- ws layout (bytes) ----------------
constexpr size_t OFF_SYNC  = 0;                                         // 8192 (64 flags @128B)
constexpr size_t OFF_MEM16 = 8192;                                      // [3840][512] f16
constexpr size_t OFF_WMSWZ = OFF_MEM16 + (size_t)3840*512*2;            // [16][512][32] f16
constexpr size_t OFF_KEYS  = OFF_WMSWZ + (size_t)16*512*32*2;           // [3840][512] f16
constexpr size_t OFF_EMBA  = OFF_KEYS  + (size_t)3840*512*2;            // [1984][320] f16
constexpr size_t OFF_WKTOP = OFF_EMBA  + (size_t)1984*320*2;            // [10][2048][32] f16 (perm)
constexpr size_t OFF_EMBW  = OFF_WKTOP + (size_t)10*2048*32*2;          // [1984][2048] f32 (perm cols)
constexpr size_t OFF_WA16  = OFF_EMBW  + (size_t)1984*2048*4;           // [1024][512] f16 rowmajor
constexpr size_t OFF_WKATT = OFF_WA16  + (size_t)1024*512*2;            // [16][2048][32] f16 (perm)
constexpr size_t OFF_WCA   = OFF_WKATT + (size_t)16*2048*32*2;          // [1024][2048] f32 (perm cols)
constexpr size_t OFF_WSTAR = OFF_WCA   + (size_t)1024*2048*4;           // [32][2048][32] f16 (perm)
constexpr size_t OFF_UK16  = OFF_WSTAR + (size_t)32*2048*32*2;          // [16][2048][32] f16 (perm)
constexpr size_t OFF_WQT   = OFF_UK16  + (size_t)16*2048*32*2;          // [512 j][512 u] f16 (Wq^T)
constexpr size_t OFF_WASWZ = OFF_WQT   + (size_t)512*512*2;             // [32][512][32] f16
constexpr size_t OFF_H016  = OFF_WASWZ + (size_t)32*512*32*2;           // [64][512] f16
constexpr size_t OFF_YALL  = OFF_H016  + (size_t)64*512*2;              // [31][64][1024] f16
constexpr size_t OFF_ZX    = OFF_YALL  + (size_t)31*64*1024*2;          // [64][2048] f32
constexpr size_t OFF_ATT16 = OFF_ZX    + (size_t)64*2048*4;             // [1984][512] f16
constexpr size_t OFF_BKP   = OFF_ATT16 + (size_t)1984*512*2;            // [2048] f32 (perm bk)
constexpr size_t OFF_WFC   = OFF_BKP   + 8192;                          // [16][34048][32] f16

// ---------------- helpers ----------------
DEV void gload16(const void* src, void* ldsbase /* wave-uniform */) {
  __builtin_amdgcn_global_load_lds(
      (const __attribute__((address_space(1))) unsigned int*)src,
      (__attribute__((address_space(3))) unsigned int*)ldsbase, 16, 0, 0);
}

DEV float sigm(float x)      { return 1.f / (1.f + expf(-x)); }
DEV float tanh_fast(float x) { float e = __expf(2.f*x); return 1.f - 2.f/(e+1.f); }

DEV uint32_t aload_u32(const uint32_t* p){ return __hip_atomic_load(p, __ATOMIC_RELAXED, __HIP_MEMORY_SCOPE_AGENT); }
DEV float    aload_f32(const float* p)   { return __hip_atomic_load(p, __ATOMIC_RELAXED, __HIP_MEMORY_SCOPE_AGENT); }
DEV void astore_u32(uint32_t* p, uint32_t v){ __hip_atomic_store(p, v, __ATOMIC_RELAXED, __HIP_MEMORY_SCOPE_AGENT); }
DEV void astore_f32(float* p, float v)      { __hip_atomic_store(p, v, __ATOMIC_RELAXED, __HIP_MEMORY_SCOPE_AGENT); }

DEV uint32_t pack16(f16 a, f16 b){ f16x2 v; v[0]=a; v[1]=b; return __builtin_bit_cast(uint32_t, v); }

// ---------------- prep: elementwise conversions ----------------
__global__ void prep_elem(char* ws, const int* dec, const float* h0,
                          const float* memory, const float* embt,
                          const float* Wq, const float* Wa, const float* bk)
{
  f16* mem16 = (f16*)(ws+OFF_MEM16);
  f16* embA  = (f16*)(ws+OFF_EMBA);
  f16* wa16  = (f16*)(ws+OFF_WA16);
  f16* wqT   = (f16*)(ws+OFF_WQT);
  f16* h016  = (f16*)(ws+OFF_H016);
  float* bkp = (float*)(ws+OFF_BKP);
  constexpr int E0=1966080, E1=E0+634880, E2=E1+524288, E3=E2+262144, E4=E3+32768, E5=E4+2048;
  for (int i = blockIdx.x*256 + threadIdx.x; i < E5; i += gridDim.x*256) {
    if (i < E0) { mem16[i] = (f16)memory[i]; }
    else if (i < E1) { int j=i-E0; int r=j/320, k=j-r*320; int t=r>>6, b=r&63;
      int tok = dec[b*TOUT+t];
      embA[j] = (k<300) ? (f16)embt[(size_t)tok*300+k] : (f16)0.f; }
    else if (i < E2) { int j=i-E1; wa16[j] = (f16)Wa[j]; }
    else if (i < E3) { int j=i-E2; int jj=j>>9, u=j&511; wqT[j] = (f16)Wq[(size_t)u*512+jj]; }
    else if (i < E4) { int j=i-E3; h016[j] = (f16)h0[j]; }
    else { int j=i-E4; bkp[j] = bk[(j>>2) + (j&3)*512]; }
  }
}

// ---------------- prep: swizzled B-layouts [K/32][N][32] ----------------
__global__ void prep_swz(char* ws, const float* Wm, const float* Wk, const float* Uk, const float* Wa)
{
  int tg = blockIdx.x*256 + threadIdx.x;
  constexpr int S0=8192, S1=S0+20480, S2=S1+32768, S3=S2+32768, S4=S3+16384;
  if (tg >= S4) return;
  f16 buf[32];
  f16* dst;
  if (tg < S0) {                       // Wm -> [16][512][32]
    int kt=tg>>9, n=tg&511;
    #pragma unroll
    for (int kk=0;kk<32;kk++) buf[kk] = (f16)Wm[(size_t)(kt*32+kk)*512 + n];
    dst = (f16*)(ws+OFF_WMSWZ) + (size_t)tg*32;
  } else if (tg < S1) {                // Wk rows 0..299 (pad->320), perm cols -> [10][2048][32]
    int j=tg-S0; int kt=j>>11, np=j&2047; int col=(np>>2)+(np&3)*512;
    #pragma unroll
    for (int kk=0;kk<32;kk++){ int k=kt*32+kk;
      buf[kk] = (k<300) ? (f16)Wk[(size_t)k*2048+col] : (f16)0.f; }
    dst = (f16*)(ws+OFF_WKTOP) + (size_t)j*32;
  } else if (tg < S2) {                // Wk rows 300..811, perm -> [16][2048][32]
    int j=tg-S1; int kt=j>>11, np=j&2047; int col=(np>>2)+(np&3)*512;
    #pragma unroll
    for (int kk=0;kk<32;kk++) buf[kk] = (f16)Wk[(size_t)(300+kt*32+kk)*2048+col];
    dst = (f16*)(ws+OFF_WKATT) + (size_t)j*32;
  } else if (tg < S3) {                // Uk, perm -> [16][2048][32]
    int j=tg-S2; int kt=j>>11, np=j&2047; int col=(np>>2)+(np&3)*512;
    #pragma unroll
    for (int kk=0;kk<32;kk++) buf[kk] = (f16)Uk[(size_t)(kt*32+kk)*2048+col];
    dst = (f16*)(ws+OFF_UK16) + (size_t)j*32;
  } else {                             // Wa -> [32][512][32]
    int j=tg-S3; int kt=j>>9, n=j&511;
    #pragma unroll
    for (int kk=0;kk<32;kk++) buf[kk] = (f16)Wa[(size_t)(kt*32+kk)*512 + n];
    dst = (f16*)(ws+OFF_WASWZ) + (size_t)j*32;
  }
  f16x8* d8 = (f16x8*)dst; f16x8* s8 = (f16x8*)buf;
  d8[0]=s8[0]; d8[1]=s8[1]; d8[2]=s8[2]; d8[3]=s8[3];
}

// ---------------- prep: Wfc -> [16][34048][32] f16 ----------------
__global__ void prep_wfc(char* ws, const float* Wfc)
{
  int n  = blockIdx.x*256 + threadIdx.x;   // 0..34047
  int kt = blockIdx.y;                      // 0..15
  f16 buf[32];
  #pragma unroll
  for (int kk=0;kk<32;kk++)
    buf[kk] = (n < VOC) ? (f16)Wfc[(size_t)(kt*32+kk)*VOC + n] : (f16)0.f;
  f16* dst = (f16*)(ws+OFF_WFC) + ((size_t)kt*VOCP + n)*32;
  f16x8* d8 = (f16x8*)dst; f16x8* s8 = (f16x8*)buf;
  d8[0]=s8[0]; d8[1]=s8[1]; d8[2]=s8[2]; d8[3]=s8[3];
}

// ---------------- build W* = Wca + [Uk;0] -> [32][2048][32] (perm) ----------------
__global__ void build_wstar(char* ws, const float* Uk)
{
  int tg = blockIdx.x*256 + threadIdx.x;   // 65536
  int kt = tg>>11, np = tg&2047;
  int col = (np>>2)+(np&3)*512;
  const float* wca = (const float*)(ws+OFF_WCA);
  f16 buf[32];
  #pragma unroll
  for (int kk=0;kk<32;kk++){
    int k = kt*32+kk;
    float v = wca[(size_t)k*2048 + np];
    if (k < 512) v += Uk[(size_t)k*2048 + col];
    buf[kk] = (f16)v;
  }
  f16* dst = (f16*)(ws+OFF_WSTAR) + (size_t)tg*32;
  f16x8* d8 = (f16x8*)dst; f16x8* s8 = (f16x8*)buf;
  d8[0]=s8[0]; d8[1]=s8[1]; d8[2]=s8[2]; d8[3]=s8[3];
}

// ---------------- generic fp16 MFMA GEMM (prologue/epilogue GEMMs) ----------------
template<int BM, int BN, int WR, int WC, int MODE>
__global__ __launch_bounds__(WR*WC*64, 1)
void gemm16(const f16* __restrict__ A, int lda,
            const f16* __restrict__ Bs, int Np,
            void* __restrict__ C, const float* __restrict__ bias,
            int M, int K, int Mreal, int Nreal)
{
  constexpr int NT  = WR*WC*64;
  constexpr int WTM = BM/WR, WTN = BN/WC, AM = WTM/16, AN = WTN/16;
  constexpr int NLA = BM*64/(NT*16), NLB = BN*64/(NT*16);
  __shared__ __align__(16) f16 sA[BM*32];
  __shared__ __align__(16) f16 sB[BN*32];
  const int tid = threadIdx.x, wave = tid>>6, lane = tid&63;
  const int lg = lane>>4, lr = lane&15;
  const int m0 = blockIdx.y*BM, n0 = blockIdx.x*BN;
  const int wm = (wave/WC)*WTM, wn = (wave%WC)*WTN;

  f32x4 acc[AM][AN] = {};

  int aoff[AM], boff[AN];
  #pragma unroll
  for (int i=0;i<AM;i++){ int row = wm+i*16+lr; aoff[i] = row*64 + (((lg + (row>>1))&3)<<4); }
  #pragma unroll
  for (int i=0;i<AN;i++){ int row = wn+i*16+lr; boff[i] = row*64 + (((lg + (row>>1))&3)<<4); }

  const int ksteps = K/32;
  for (int ks=0; ks<ksteps; ks++){
    const int k0 = ks*32;
    __syncthreads();
    #pragma unroll
    for (int i=0;i<NLA;i++){
      int p = i*NT + tid;
      int row = p>>2; int g = ((p&3) - (row>>1)) & 3;
      int gm = m0+row; if (gm > Mreal-1) gm = Mreal-1;
      gload16(A + (size_t)gm*lda + k0 + g*8, (char*)sA + (i*NT + wave*64)*16);
    }
    #pragma unroll
    for (int i=0;i<NLB;i++){
      int p = i*NT + tid;
      int row = p>>2; int g = ((p&3) - (row>>1)) & 3;
      gload16(Bs + ((size_t)(k0>>5)*Np + (n0+row))*32 + g*8, (char*)sB + (i*NT + wave*64)*16);
    }
    __syncthreads();
    f16x8 af[AM], bf[AN];
    #pragma unroll
    for (int i=0;i<AM;i++) af[i] = *(const f16x8*)((const char*)sA + aoff[i]);
    #pragma unroll
    for (int i=0;i<AN;i++) bf[i] = *(const f16x8*)((const char*)sB + boff[i]);
    #pragma unroll
    for (int i=0;i<AM;i++)
      #pragma unroll
      for (int j=0;j<AN;j++)
        acc[i][j] = __builtin_amdgcn_mfma_f32_16x16x32_f16(af[i], bf[j], acc[i][j], 0,0,0);
  }

  #pragma unroll
  for (int i=0;i<AM;i++)
    #pragma unroll
    for (int j=0;j<AN;j++){
      int n = n0 + wn + j*16 + lr;
      if (MODE == 2 && n >= Nreal) continue;
      float bb = 0.f;
      if (MODE != 1 && bias) bb = bias[n];
      #pragma unroll
      for (int r=0;r<4;r++){
        int m = m0 + wm + i*16 + lg*4 + r;
        if (m >= Mreal) continue;
        float v = acc[i][j][r] + bb;
        if (MODE == 0)      ((float*)C)[(size_t)m*Np + n] = v;
        else if (MODE == 1) ((f16*)C)[(size_t)m*Np + n] = (f16)v;
        else { int t = m>>6, b = m&63; ((float*)C)[((size_t)(b*TOUT+t))*VOC + n] = v; }
      }
    }
}

// ---------------- cluster barrier: flag array, no L2 fences ----------------
DEV void cbar(uint32_t* flags, int cbase, int jsl, int tid, uint32_t target)
{
  // drain this wave's outstanding (atomic) stores, then publish
  asm volatile("s_waitcnt vmcnt(0)" ::: "memory");
  __syncthreads();
  if (tid == 0)
    __hip_atomic_store(flags + (size_t)(cbase + jsl)*32, target,
                       __ATOMIC_RELEASE, __HIP_MEMORY_SCOPE_AGENT);
  if (tid < 16) {
    while (aload_u32(flags + (size_t)(cbase + tid)*32) < target)
      __builtin_amdgcn_s_sleep(1);
  }
  __syncthreads();
}

// ---------------- P1 inner: per-wave 16x16 tile over K, 8-deep B prefetch ----------------
template<int KS>
DEV f32x4 p1_mfma(const f16* __restrict__ Bs, const char* ylb, int col, int kg, int lr)
{
  f16x8 B[8];
  #pragma unroll
  for (int i=0;i<8;i++)
    B[i] = *(const f16x8*)(Bs + (((size_t)i*2048 + col)<<5) + kg*8);
  f32x4 acc = {};
  #pragma unroll
  for (int ks=0; ks<KS; ks+=8) {
    #pragma unroll
    for (int i=0;i<8;i++) {
      f16x8 a = *(const f16x8*)(ylb + lr*2064 + (ks+i)*64 + kg*16);
      acc = __builtin_amdgcn_mfma_f32_16x16x32_f16(a, B[i], acc, 0,0,0);
      int nk = ks+8+i;
      if (nk < KS)
        B[i] = *(const f16x8*)(Bs + (((size_t)nk*2048 + col)<<5) + kg*8);
    }
  }
  return acc;
}

// ---------------- persistent recurrence: 64 blocks x 512 thr, 4 indep clusters ----------------
__global__ __launch_bounds__(512, 1)
void recur(char* ws, const float* __restrict__ c0, const float* __restrict__ v_att)
{
  const int blk = blockIdx.x, tid = threadIdx.x;
  const int wave = tid>>6, lane = tid&63;
  const int lr = lane&15, kg = lane>>4;
  const int clus = blk>>4, jsl = blk&15;
  const int cbase = clus<<4;
  const int bown = cbase | jsl;          // batch owned in P2
  const int n0 = jsl*128;                // n-slice owned in P1

  uint32_t* flags = (uint32_t*)(ws+OFF_SYNC);
  float* zx = (float*)(ws+OFF_ZX);
  const f16* wstar = (const f16*)(ws+OFF_WSTAR);
  const f16* uk16  = (const f16*)(ws+OFF_UK16);
  const f16* wqT   = (const f16*)(ws+OFF_WQT);
  const f16* keys16= (const f16*)(ws+OFF_KEYS);
  const f16* mem16 = (const f16*)(ws+OFF_MEM16);
  const float* embw= (const float*)(ws+OFF_EMBW);

  __shared__ __align__(16) char  yl[16*2064];    // 16 batches x 1032 f16 (stride 2064B, odd 16B slots)
  __shared__ __align__(16) float c_l[512];
  __shared__ __align__(16) float q_l[512];
  __shared__ __align__(16) float v_l[512];
  __shared__ __align__(16) f16   h16_l[512];
  __shared__ __align__(16) f16   cx16_l[512];
  __shared__ __align__(16) float sc_l[64];

  v_l[tid] = v_att[tid];

  for (int t=0; t<TOUT; t++){
    // ---------- P1: gather y(t-1) for the cluster's 16 batches ----------
    {
      const uint32_t* ysrc; int rw;
      if (t == 0) { ysrc = (const uint32_t*)(ws+OFF_H016); rw = 256; }
      else        { ysrc = (const uint32_t*)(ws+OFF_YALL + (size_t)(t-1)*64*1024*2); rw = 512; }
      if (tid < rw) {
        uint32_t g[16];
        #pragma unroll
        for (int r=0;r<16;r++) g[r] = aload_u32(ysrc + (size_t)(cbase+r)*rw + tid);
        #pragma unroll
        for (int r=0;r<16;r++) *(uint32_t*)(yl + r*2064 + tid*4) = g[r];
      }
      __syncthreads();
    }

    // ---------- P1: z-slice = Y_c(16x K) @ W*[:, n0+wave*16 ..] ----------
    {
      const int col = n0 + wave*16 + lr;
      f32x4 acc = (t==0) ? p1_mfma<16>(uk16,  yl, col, kg, lr)
                         : p1_mfma<32>(wstar, yl, col, kg, lr);
      const int rbase = cbase + (lane>>4)*4;
      #pragma unroll
      for (int r=0;r<4;r++)
        astore_f32(zx + (size_t)(rbase+r)*2048 + col, acc[r]);
    }
    cbar(flags, cbase, jsl, tid, 2*t+1);

    // ---------- P2: own batch: gates -> h -> q -> scores -> ctx ----------
    {
      // gates (thread = unit u)
      float z0 = aload_f32(zx + (size_t)bown*2048 + tid*4 + 0);
      float z1 = aload_f32(zx + (size_t)bown*2048 + tid*4 + 1);
      float z2 = aload_f32(zx + (size_t)bown*2048 + tid*4 + 2);
      float z3 = aload_f32(zx + (size_t)bown*2048 + tid*4 + 3);
      f32x4 e  = *(const f32x4*)(embw + ((size_t)(t*64+bown))*2048 + tid*4);
      float ig = sigm(z0+e[0]), fg = sigm(z1+e[1]);
      float gg = tanhf(z2+e[2]), og = sigm(z3+e[3]);
      float cold = (t==0) ? c0[bown*512+tid] : c_l[tid];
      float cn = fg*cold + ig*gg;
      c_l[tid] = cn;
      f16 h16 = (f16)(og * tanhf(cn));
      h16_l[tid] = h16;
      __syncthreads();

      uint32_t* yb = (uint32_t*)(ws+OFF_YALL) + ((size_t)t*64 + bown)*512;
      if (tid < 256) astore_u32(yb + tid, pack16(h16_l[2*tid], h16_l[2*tid+1]));

      // q[j] = h . Wq[:,j]
      {
        const f16x8* wrow = (const f16x8*)(wqT + (size_t)tid*512);
        const f16x8* h8   = (const f16x8*)h16_l;
        float qa = 0.f;
        #pragma unroll 8
        for (int u8=0; u8<64; u8++){
          f16x8 w = wrow[u8]; f16x8 h = h8[u8];
          qa = __builtin_amdgcn_fdot2(f16x2{w[0],w[1]}, f16x2{h[0],h[1]}, qa, false);
          qa = __builtin_amdgcn_fdot2(f16x2{w[2],w[3]}, f16x2{h[2],h[3]}, qa, false);
          qa = __builtin_amdgcn_fdot2(f16x2{w[4],w[5]}, f16x2{h[4],h[5]}, qa, false);
          qa = __builtin_amdgcn_fdot2(f16x2{w[6],w[7]}, f16x2{h[6],h[7]}, qa, false);
        }
        q_l[tid] = qa;
      }
      __syncthreads();

      // scores: one wave per memory row i
      for (int i = wave; i < 60; i += 8){
        const f16* krow = keys16 + ((size_t)(bown*60+i))*512;
        float p = 0.f;
        #pragma unroll
        for (int s=0;s<8;s++){
          int u = lane + s*64;
          p += tanh_fast((float)krow[u] + q_l[u]) * v_l[u];
        }
        #pragma unroll
        for (int m=32;m;m>>=1) p += __shfl_xor(p, m, 64);
        if (lane == 0) sc_l[i] = p;
      }
      __syncthreads();
      if (wave == 0){
        float s = (lane < 60) ? sc_l[lane] : -1e30f;
        float mx = s;
        #pragma unroll
        for (int m=32;m;m>>=1) mx = fmaxf(mx, __shfl_xor(mx, m, 64));
        float ev = (lane < 60) ? __expf(s - mx) : 0.f;
        float sum = ev;
        #pragma unroll
        for (int m=32;m;m>>=1) sum += __shfl_xor(sum, m, 64);
        if (lane < 60) sc_l[lane] = ev / sum;
      }
      __syncthreads();

      // ctx[d] = sum_i align[i]*memory[b,i,d]
      {
        float cx = 0.f;
        const f16* mrow = mem16 + ((size_t)bown*60)*512 + tid;
        #pragma unroll 4
        for (int i=0;i<60;i++) cx += sc_l[i] * (float)mrow[(size_t)i*512];
        cx16_l[tid] = (f16)cx;
      }
      __syncthreads();
      if (tid < 256) astore_u32(yb + 256 + tid, pack16(cx16_l[2*tid], cx16_l[2*tid+1]));
    }
    cbar(flags, cbase, jsl, tid, 2*t+2);
  }
}

// ---------------- host ----------------
extern "C" void kernel_launch(void* const* d_in, const int* in_sizes, int n_in,
                              void* d_out, int out_size, void* d_ws, size_t ws_size,
                              hipStream_t stream)
{
  const int*   dec  = (const int*)  d_in[0];
  const float* h0   = (const float*)d_in[1];
  const float* c0   = (const float*)d_in[2];
  const float* mem  = (const float*)d_in[3];
  const float* embt = (const float*)d_in[4];
  const float* Wk   = (const float*)d_in[5];
  const float* Uk   = (const float*)d_in[6];
  const float* bk   = (const float*)d_in[7];
  const float* Wm   = (const float*)d_in[8];
  const float* Wq   = (const float*)d_in[9];
  const float* va   = (const float*)d_in[10];
  const float* Wa   = (const float*)d_in[11];
  const float* Wfc  = (const float*)d_in[12];
  const float* bfc  = (const float*)d_in[13];
  char* ws = (char*)d_ws;

  hipMemsetAsync(ws + OFF_SYNC, 0, 8192, stream);

  prep_elem<<<4096, 256, 0, stream>>>(ws, dec, h0, mem, embt, Wq, Wa, bk);
  prep_swz <<<432, 256, 0, stream>>>(ws, Wm, Wk, Uk, Wa);
  prep_wfc <<<dim3(133,16), 256, 0, stream>>>(ws, Wfc);

  // keys = memory @ Wm : [3840,512] f16
  gemm16<128,64,2,2,1><<<dim3(8,30), 256, 0, stream>>>(
      (const f16*)(ws+OFF_MEM16), 512, (const f16*)(ws+OFF_WMSWZ), 512,
      ws+OFF_KEYS, nullptr, 3840, 512, 3840, 512);
  // embW = embA @ WkTop + bk_perm : [1984,2048] f32 (perm cols)
  gemm16<128,64,2,2,0><<<dim3(32,16), 256, 0, stream>>>(
      (const f16*)(ws+OFF_EMBA), 320, (const f16*)(ws+OFF_WKTOP), 2048,
      ws+OFF_EMBW, (const float*)(ws+OFF_BKP), 1984, 320, 1984, 2048);
  // Wca = Wa @ WkAttn : [1024,2048] f32 (perm cols)
  gemm16<128,64,2,2,0><<<dim3(32,8), 256, 0, stream>>>(
      (const f16*)(ws+OFF_WA16), 512, (const f16*)(ws+OFF_WKATT), 2048,
      ws+OFF_WCA, nullptr, 1024, 512, 1024, 2048);
  build_wstar<<<256, 256, 0, stream>>>(ws, Uk);

  recur<<<64, 512, 0, stream>>>(ws, c0, va);

  // attn_all = Y @ Wa : [1984,512] f16
  gemm16<128,64,2,2,1><<<dim3(8,16), 256, 0, stream>>>(
      (const f16*)(ws+OFF_YALL), 1024, (const f16*)(ws+OFF_WASWZ), 512,
      ws+OFF_ATT16, nullptr, 1984, 1024, 1984, 512);
  // logits = attn_all @ Wfc + bfc -> d_out [b][t][vocab]
  gemm16<128,256,2,4,2><<<dim3(133,16), 512, 0, stream>>>(
      (const f16*)(ws+OFF_ATT16), 512, (const f16*)(ws+OFF_WFC), VOCP,
      d_out, bfc, 1984, 512, 1984, VOC);
}

// Round 3
// 1260.838 us; speedup vs baseline: 1.6624x; 1.0283x over previous
//
#include <hip/hip_runtime.h>
#include <cstdint>
#include <cstddef>

typedef _Float16 f16;
typedef _Float16 f16x8 __attribute__((ext_vector_type(8)));
typedef _Float16 f16x2 __attribute__((ext_vector_type(2)));
typedef float    f32x4 __attribute__((ext_vector_type(4)));

#define DEV static __device__ __forceinline__

constexpr int TOUT = 31;
constexpr int VOC  = 34004;
constexpr int VOCP = 34048;

// ---------------- ws layout (bytes) ----------------
constexpr size_t OFF_SYNC  = 0;                                         // 8192 (64 flags @128B)
constexpr size_t OFF_MEM16 = 8192;                                      // [3840][512] f16
constexpr size_t OFF_WMSWZ = OFF_MEM16 + (size_t)3840*512*2;            // [16][512][32] f16
constexpr size_t OFF_KEYS  = OFF_WMSWZ + (size_t)16*512*32*2;           // [3840][512] f16
constexpr size_t OFF_EMBA  = OFF_KEYS  + (size_t)3840*512*2;            // [1984][320] f16
constexpr size_t OFF_WKTOP = OFF_EMBA  + (size_t)1984*320*2;            // [10][2048][32] f16 (perm)
constexpr size_t OFF_EMBW  = OFF_WKTOP + (size_t)10*2048*32*2;          // [1984][2048] f32 (perm cols)
constexpr size_t OFF_WA16  = OFF_EMBW  + (size_t)1984*2048*4;           // [1024][512] f16 rowmajor
constexpr size_t OFF_WKATT = OFF_WA16  + (size_t)1024*512*2;            // [16][2048][32] f16 (perm)
constexpr size_t OFF_WCA   = OFF_WKATT + (size_t)16*2048*32*2;          // [1024][2048] f32 (perm cols)
constexpr size_t OFF_WSTAR = OFF_WCA   + (size_t)1024*2048*4;           // [32][2048][32] f16 (perm)
constexpr size_t OFF_UK16  = OFF_WSTAR + (size_t)32*2048*32*2;          // [16][2048][32] f16 (perm)
constexpr size_t OFF_WQT   = OFF_UK16  + (size_t)16*2048*32*2;          // [512 j][512 u] f16 (Wq^T)
constexpr size_t OFF_WASWZ = OFF_WQT   + (size_t)512*512*2;             // [32][512][32] f16
constexpr size_t OFF_H016  = OFF_WASWZ + (size_t)32*512*32*2;           // [64][512] f16
constexpr size_t OFF_YALL  = OFF_H016  + (size_t)64*512*2;              // [31][64][1024] f16
constexpr size_t OFF_ZX    = OFF_YALL  + (size_t)31*64*1024*2;          // [64][2048] f32
constexpr size_t OFF_ATT16 = OFF_ZX    + (size_t)64*2048*4;             // [1984][512] f16
constexpr size_t OFF_BKP   = OFF_ATT16 + (size_t)1984*512*2;            // [2048] f32 (perm bk)
constexpr size_t OFF_WFC   = OFF_BKP   + 8192;                          // [16][34048][32] f16

// ---------------- helpers ----------------
DEV void gload16(const void* src, void* ldsbase /* wave-uniform */) {
  __builtin_amdgcn_global_load_lds(
      (const __attribute__((address_space(1))) unsigned int*)src,
      (__attribute__((address_space(3))) unsigned int*)ldsbase, 16, 0, 0);
}

DEV float sigm(float x)      { return 1.f / (1.f + expf(-x)); }
DEV float tanh_fast(float x) { float e = __expf(2.f*x); return 1.f - 2.f/(e+1.f); }

DEV uint32_t aload_u32(const uint32_t* p){ return __hip_atomic_load(p, __ATOMIC_RELAXED, __HIP_MEMORY_SCOPE_AGENT); }
DEV float    aload_f32(const float* p)   { return __hip_atomic_load(p, __ATOMIC_RELAXED, __HIP_MEMORY_SCOPE_AGENT); }
DEV void astore_u32(uint32_t* p, uint32_t v){ __hip_atomic_store(p, v, __ATOMIC_RELAXED, __HIP_MEMORY_SCOPE_AGENT); }
DEV void astore_f32(float* p, float v)      { __hip_atomic_store(p, v, __ATOMIC_RELAXED, __HIP_MEMORY_SCOPE_AGENT); }

DEV uint32_t pack16(f16 a, f16 b){ f16x2 v; v[0]=a; v[1]=b; return __builtin_bit_cast(uint32_t, v); }

// ---------------- prep: elementwise conversions ----------------
__global__ void prep_elem(char* ws, const int* dec, const float* h0,
                          const float* memory, const float* embt,
                          const float* Wq, const float* Wa, const float* bk)
{
  f16* mem16 = (f16*)(ws+OFF_MEM16);
  f16* embA  = (f16*)(ws+OFF_EMBA);
  f16* wa16  = (f16*)(ws+OFF_WA16);
  f16* wqT   = (f16*)(ws+OFF_WQT);
  f16* h016  = (f16*)(ws+OFF_H016);
  float* bkp = (float*)(ws+OFF_BKP);
  constexpr int E0=1966080, E1=E0+634880, E2=E1+524288, E3=E2+262144, E4=E3+32768, E5=E4+2048;
  for (int i = blockIdx.x*256 + threadIdx.x; i < E5; i += gridDim.x*256) {
    if (i < E0) { mem16[i] = (f16)memory[i]; }
    else if (i < E1) { int j=i-E0; int r=j/320, k=j-r*320; int t=r>>6, b=r&63;
      int tok = dec[b*TOUT+t];
      embA[j] = (k<300) ? (f16)embt[(size_t)tok*300+k] : (f16)0.f; }
    else if (i < E2) { int j=i-E1; wa16[j] = (f16)Wa[j]; }
    else if (i < E3) { int j=i-E2; int jj=j>>9, u=j&511; wqT[j] = (f16)Wq[(size_t)u*512+jj]; }
    else if (i < E4) { int j=i-E3; h016[j] = (f16)h0[j]; }
    else { int j=i-E4; bkp[j] = bk[(j>>2) + (j&3)*512]; }
  }
}

// ---------------- prep: swizzled B-layouts [K/32][N][32] ----------------
__global__ void prep_swz(char* ws, const float* Wm, const float* Wk, const float* Uk, const float* Wa)
{
  int tg = blockIdx.x*256 + threadIdx.x;
  constexpr int S0=8192, S1=S0+20480, S2=S1+32768, S3=S2+32768, S4=S3+16384;
  if (tg >= S4) return;
  f16 buf[32];
  f16* dst;
  if (tg < S0) {                       // Wm -> [16][512][32]
    int kt=tg>>9, n=tg&511;
    #pragma unroll
    for (int kk=0;kk<32;kk++) buf[kk] = (f16)Wm[(size_t)(kt*32+kk)*512 + n];
    dst = (f16*)(ws+OFF_WMSWZ) + (size_t)tg*32;
  } else if (tg < S1) {                // Wk rows 0..299 (pad->320), perm cols -> [10][2048][32]
    int j=tg-S0; int kt=j>>11, np=j&2047; int col=(np>>2)+(np&3)*512;
    #pragma unroll
    for (int kk=0;kk<32;kk++){ int k=kt*32+kk;
      buf[kk] = (k<300) ? (f16)Wk[(size_t)k*2048+col] : (f16)0.f; }
    dst = (f16*)(ws+OFF_WKTOP) + (size_t)j*32;
  } else if (tg < S2) {                // Wk rows 300..811, perm -> [16][2048][32]
    int j=tg-S1; int kt=j>>11, np=j&2047; int col=(np>>2)+(np&3)*512;
    #pragma unroll
    for (int kk=0;kk<32;kk++) buf[kk] = (f16)Wk[(size_t)(300+kt*32+kk)*2048+col];
    dst = (f16*)(ws+OFF_WKATT) + (size_t)j*32;
  } else if (tg < S3) {                // Uk, perm -> [16][2048][32]
    int j=tg-S2; int kt=j>>11, np=j&2047; int col=(np>>2)+(np&3)*512;
    #pragma unroll
    for (int kk=0;kk<32;kk++) buf[kk] = (f16)Uk[(size_t)(kt*32+kk)*2048+col];
    dst = (f16*)(ws+OFF_UK16) + (size_t)j*32;
  } else {                             // Wa -> [32][512][32]
    int j=tg-S3; int kt=j>>9, n=j&511;
    #pragma unroll
    for (int kk=0;kk<32;kk++) buf[kk] = (f16)Wa[(size_t)(kt*32+kk)*512 + n];
    dst = (f16*)(ws+OFF_WASWZ) + (size_t)j*32;
  }
  f16x8* d8 = (f16x8*)dst; f16x8* s8 = (f16x8*)buf;
  d8[0]=s8[0]; d8[1]=s8[1]; d8[2]=s8[2]; d8[3]=s8[3];
}

// ---------------- prep: Wfc -> [16][34048][32] f16 ----------------
__global__ void prep_wfc(char* ws, const float* Wfc)
{
  int n  = blockIdx.x*256 + threadIdx.x;   // 0..34047
  int kt = blockIdx.y;                      // 0..15
  f16 buf[32];
  #pragma unroll
  for (int kk=0;kk<32;kk++)
    buf[kk] = (n < VOC) ? (f16)Wfc[(size_t)(kt*32+kk)*VOC + n] : (f16)0.f;
  f16* dst = (f16*)(ws+OFF_WFC) + ((size_t)kt*VOCP + n)*32;
  f16x8* d8 = (f16x8*)dst; f16x8* s8 = (f16x8*)buf;
  d8[0]=s8[0]; d8[1]=s8[1]; d8[2]=s8[2]; d8[3]=s8[3];
}

// ---------------- build W* = Wca + [Uk;0] -> [32][2048][32] (perm) ----------------
__global__ void build_wstar(char* ws, const float* Uk)
{
  int tg = blockIdx.x*256 + threadIdx.x;   // 65536
  int kt = tg>>11, np = tg&2047;
  int col = (np>>2)+(np&3)*512;
  const float* wca = (const float*)(ws+OFF_WCA);
  f16 buf[32];
  #pragma unroll
  for (int kk=0;kk<32;kk++){
    int k = kt*32+kk;
    float v = wca[(size_t)k*2048 + np];
    if (k < 512) v += Uk[(size_t)k*2048 + col];
    buf[kk] = (f16)v;
  }
  f16* dst = (f16*)(ws+OFF_WSTAR) + (size_t)tg*32;
  f16x8* d8 = (f16x8*)dst; f16x8* s8 = (f16x8*)buf;
  d8[0]=s8[0]; d8[1]=s8[1]; d8[2]=s8[2]; d8[3]=s8[3];
}

// ---------------- generic fp16 MFMA GEMM (prologue/epilogue GEMMs) ----------------
template<int BM, int BN, int WR, int WC, int MODE>
__global__ __launch_bounds__(WR*WC*64, 1)
void gemm16(const f16* __restrict__ A, int lda,
            const f16* __restrict__ Bs, int Np,
            void* __restrict__ C, const float* __restrict__ bias,
            int M, int K, int Mreal, int Nreal)
{
  constexpr int NT  = WR*WC*64;
  constexpr int WTM = BM/WR, WTN = BN/WC, AM = WTM/16, AN = WTN/16;
  constexpr int NLA = BM*64/(NT*16), NLB = BN*64/(NT*16);
  __shared__ __align__(16) f16 sA[BM*32];
  __shared__ __align__(16) f16 sB[BN*32];
  const int tid = threadIdx.x, wave = tid>>6, lane = tid&63;
  const int lg = lane>>4, lr = lane&15;
  const int m0 = blockIdx.y*BM, n0 = blockIdx.x*BN;
  const int wm = (wave/WC)*WTM, wn = (wave%WC)*WTN;

  f32x4 acc[AM][AN] = {};

  int aoff[AM], boff[AN];
  #pragma unroll
  for (int i=0;i<AM;i++){ int row = wm+i*16+lr; aoff[i] = row*64 + (((lg + (row>>1))&3)<<4); }
  #pragma unroll
  for (int i=0;i<AN;i++){ int row = wn+i*16+lr; boff[i] = row*64 + (((lg + (row>>1))&3)<<4); }

  const int ksteps = K/32;
  for (int ks=0; ks<ksteps; ks++){
    const int k0 = ks*32;
    __syncthreads();
    #pragma unroll
    for (int i=0;i<NLA;i++){
      int p = i*NT + tid;
      int row = p>>2; int g = ((p&3) - (row>>1)) & 3;
      int gm = m0+row; if (gm > Mreal-1) gm = Mreal-1;
      gload16(A + (size_t)gm*lda + k0 + g*8, (char*)sA + (i*NT + wave*64)*16);
    }
    #pragma unroll
    for (int i=0;i<NLB;i++){
      int p = i*NT + tid;
      int row = p>>2; int g = ((p&3) - (row>>1)) & 3;
      gload16(Bs + ((size_t)(k0>>5)*Np + (n0+row))*32 + g*8, (char*)sB + (i*NT + wave*64)*16);
    }
    __syncthreads();
    f16x8 af[AM], bf[AN];
    #pragma unroll
    for (int i=0;i<AM;i++) af[i] = *(const f16x8*)((const char*)sA + aoff[i]);
    #pragma unroll
    for (int i=0;i<AN;i++) bf[i] = *(const f16x8*)((const char*)sB + boff[i]);
    #pragma unroll
    for (int i=0;i<AM;i++)
      #pragma unroll
      for (int j=0;j<AN;j++)
        acc[i][j] = __builtin_amdgcn_mfma_f32_16x16x32_f16(af[i], bf[j], acc[i][j], 0,0,0);
  }

  #pragma unroll
  for (int i=0;i<AM;i++)
    #pragma unroll
    for (int j=0;j<AN;j++){
      int n = n0 + wn + j*16 + lr;
      if (MODE == 2 && n >= Nreal) continue;
      float bb = 0.f;
      if (MODE != 1 && bias) bb = bias[n];
      #pragma unroll
      for (int r=0;r<4;r++){
        int m = m0 + wm + i*16 + lg*4 + r;
        if (m >= Mreal) continue;
        float v = acc[i][j][r] + bb;
        if (MODE == 0)      ((float*)C)[(size_t)m*Np + n] = v;
        else if (MODE == 1) ((f16*)C)[(size_t)m*Np + n] = (f16)v;
        else { int t = m>>6, b = m&63; ((float*)C)[((size_t)(b*TOUT+t))*VOC + n] = v; }
      }
    }
}

// ---------------- cluster barrier: flag array, relaxed only, no L2 fences ----------------
// Correctness: all cross-block data is written with agent-scope (sc1) relaxed
// atomic stores that commit at the coherence point; each wave drains its own
// stores with vmcnt(0) below before the block barrier, so once tid 0 publishes
// the (relaxed) flag, all of this block's data is globally visible.
DEV void cbar(uint32_t* flags, int cbase, int jsl, int tid, uint32_t target)
{
  asm volatile("s_waitcnt vmcnt(0)" ::: "memory");
  __syncthreads();
  if (tid == 0)
    astore_u32(flags + (size_t)(cbase + jsl)*32, target);
  if (tid < 16) {
    while (aload_u32(flags + (size_t)(cbase + tid)*32) < target)
      __builtin_amdgcn_s_sleep(1);
  }
  __syncthreads();
}

// ---------------- P1 inner: per-wave 16x16 tile over K, 8-deep B prefetch ----------------
template<int KS>
DEV f32x4 p1_mfma(const f16* __restrict__ Bs, const char* ylb, int col, int kg, int lr)
{
  f16x8 B[8];
  #pragma unroll
  for (int i=0;i<8;i++)
    B[i] = *(const f16x8*)(Bs + (((size_t)i*2048 + col)<<5) + kg*8);
  f32x4 acc = {};
  #pragma unroll
  for (int ks=0; ks<KS; ks+=8) {
    #pragma unroll
    for (int i=0;i<8;i++) {
      f16x8 a = *(const f16x8*)(ylb + lr*2064 + (ks+i)*64 + kg*16);
      acc = __builtin_amdgcn_mfma_f32_16x16x32_f16(a, B[i], acc, 0,0,0);
      int nk = ks+8+i;
      if (nk < KS)
        B[i] = *(const f16x8*)(Bs + (((size_t)nk*2048 + col)<<5) + kg*8);
    }
  }
  return acc;
}

// ---------------- persistent recurrence: 64 blocks x 512 thr, 4 indep clusters ----------------
__global__ __launch_bounds__(512, 1)
void recur(char* ws, const float* __restrict__ c0, const float* __restrict__ v_att)
{
  const int blk = blockIdx.x, tid = threadIdx.x;
  const int wave = tid>>6, lane = tid&63;
  const int lr = lane&15, kg = lane>>4;
  const int clus = blk>>4, jsl = blk&15;
  const int cbase = clus<<4;
  const int bown = cbase | jsl;          // batch owned in P2
  const int n0 = jsl*128;                // n-slice owned in P1

  uint32_t* flags = (uint32_t*)(ws+OFF_SYNC);
  float* zx = (float*)(ws+OFF_ZX);
  const f16* wstar = (const f16*)(ws+OFF_WSTAR);
  const f16* uk16  = (const f16*)(ws+OFF_UK16);
  const f16* wqT   = (const f16*)(ws+OFF_WQT);
  const f16* keys16= (const f16*)(ws+OFF_KEYS);
  const f16* mem16 = (const f16*)(ws+OFF_MEM16);
  const float* embw= (const float*)(ws+OFF_EMBW);

  __shared__ __align__(16) char  yl[16*2064];    // 16 batches x 1032 f16 (stride 2064B, odd 16B slots)
  __shared__ __align__(16) float c_l[512];
  __shared__ __align__(16) float q_l[512];
  __shared__ __align__(16) float v_l[512];
  __shared__ __align__(16) f16   h16_l[512];
  __shared__ __align__(16) f16   cx16_l[512];
  __shared__ __align__(16) float sc_l[64];

  v_l[tid] = v_att[tid];

  for (int t=0; t<TOUT; t++){
    // ---------- P1: gather y(t-1) for the cluster's 16 batches ----------
    {
      const uint32_t* ysrc; int rw;
      if (t == 0) { ysrc = (const uint32_t*)(ws+OFF_H016); rw = 256; }
      else        { ysrc = (const uint32_t*)(ws+OFF_YALL + (size_t)(t-1)*64*1024*2); rw = 512; }
      if (tid < rw) {
        uint32_t g[16];
        #pragma unroll
        for (int r=0;r<16;r++) g[r] = aload_u32(ysrc + (size_t)(cbase+r)*rw + tid);
        #pragma unroll
        for (int r=0;r<16;r++) *(uint32_t*)(yl + r*2064 + tid*4) = g[r];
      }
      __syncthreads();
    }

    // ---------- P1: z-slice = Y_c(16x K) @ W*[:, n0+wave*16 ..] ----------
    {
      const int col = n0 + wave*16 + lr;
      f32x4 acc = (t==0) ? p1_mfma<16>(uk16,  yl, col, kg, lr)
                         : p1_mfma<32>(wstar, yl, col, kg, lr);
      const int rbase = cbase + (lane>>4)*4;
      #pragma unroll
      for (int r=0;r<4;r++)
        astore_f32(zx + (size_t)(rbase+r)*2048 + col, acc[r]);
    }
    cbar(flags, cbase, jsl, tid, 2*t+1);

    // ---------- P2: own batch: gates -> h -> q -> scores -> ctx ----------
    {
      // gates (thread = unit u)
      float z0 = aload_f32(zx + (size_t)bown*2048 + tid*4 + 0);
      float z1 = aload_f32(zx + (size_t)bown*2048 + tid*4 + 1);
      float z2 = aload_f32(zx + (size_t)bown*2048 + tid*4 + 2);
      float z3 = aload_f32(zx + (size_t)bown*2048 + tid*4 + 3);
      f32x4 e  = *(const f32x4*)(embw + ((size_t)(t*64+bown))*2048 + tid*4);
      float ig = sigm(z0+e[0]), fg = sigm(z1+e[1]);
      float gg = tanhf(z2+e[2]), og = sigm(z3+e[3]);
      float cold = (t==0) ? c0[bown*512+tid] : c_l[tid];
      float cn = fg*cold + ig*gg;
      c_l[tid] = cn;
      f16 h16 = (f16)(og * tanhf(cn));
      h16_l[tid] = h16;
      __syncthreads();

      uint32_t* yb = (uint32_t*)(ws+OFF_YALL) + ((size_t)t*64 + bown)*512;
      if (tid < 256) astore_u32(yb + tid, pack16(h16_l[2*tid], h16_l[2*tid+1]));

      // q[j] = h . Wq[:,j]
      {
        const f16x8* wrow = (const f16x8*)(wqT + (size_t)tid*512);
        const f16x8* h8   = (const f16x8*)h16_l;
        float qa = 0.f;
        #pragma unroll 8
        for (int u8=0; u8<64; u8++){
          f16x8 w = wrow[u8]; f16x8 h = h8[u8];
          qa = __builtin_amdgcn_fdot2(f16x2{w[0],w[1]}, f16x2{h[0],h[1]}, qa, false);
          qa = __builtin_amdgcn_fdot2(f16x2{w[2],w[3]}, f16x2{h[2],h[3]}, qa, false);
          qa = __builtin_amdgcn_fdot2(f16x2{w[4],w[5]}, f16x2{h[4],h[5]}, qa, false);
          qa = __builtin_amdgcn_fdot2(f16x2{w[6],w[7]}, f16x2{h[6],h[7]}, qa, false);
        }
        q_l[tid] = qa;
      }
      __syncthreads();

      // scores: one wave per memory row i
      for (int i = wave; i < 60; i += 8){
        const f16* krow = keys16 + ((size_t)(bown*60+i))*512;
        float p = 0.f;
        #pragma unroll
        for (int s=0;s<8;s++){
          int u = lane + s*64;
          p += tanh_fast((float)krow[u] + q_l[u]) * v_l[u];
        }
        #pragma unroll
        for (int m=32;m;m>>=1) p += __shfl_xor(p, m, 64);
        if (lane == 0) sc_l[i] = p;
      }
      __syncthreads();
      if (wave == 0){
        float s = (lane < 60) ? sc_l[lane] : -1e30f;
        float mx = s;
        #pragma unroll
        for (int m=32;m;m>>=1) mx = fmaxf(mx, __shfl_xor(mx, m, 64));
        float ev = (lane < 60) ? __expf(s - mx) : 0.f;
        float sum = ev;
        #pragma unroll
        for (int m=32;m;m>>=1) sum += __shfl_xor(sum, m, 64);
        if (lane < 60) sc_l[lane] = ev / sum;
      }
      __syncthreads();

      // ctx[d] = sum_i align[i]*memory[b,i,d]
      {
        float cx = 0.f;
        const f16* mrow = mem16 + ((size_t)bown*60)*512 + tid;
        #pragma unroll 4
        for (int i=0;i<60;i++) cx += sc_l[i] * (float)mrow[(size_t)i*512];
        cx16_l[tid] = (f16)cx;
      }
      __syncthreads();
      if (tid < 256) astore_u32(yb + 256 + tid, pack16(cx16_l[2*tid], cx16_l[2*tid+1]));
    }
    cbar(flags, cbase, jsl, tid, 2*t+2);
  }
}

// ---------------- host ----------------
extern "C" void kernel_launch(void* const* d_in, const int* in_sizes, int n_in,
                              void* d_out, int out_size, void* d_ws, size_t ws_size,
                              hipStream_t stream)
{
  const int*   dec  = (const int*)  d_in[0];
  const float* h0   = (const float*)d_in[1];
  const float* c0   = (const float*)d_in[2];
  const float* mem  = (const float*)d_in[3];
  const float* embt = (const float*)d_in[4];
  const float* Wk   = (const float*)d_in[5];
  const float* Uk   = (const float*)d_in[6];
  const float* bk   = (const float*)d_in[7];
  const float* Wm   = (const float*)d_in[8];
  const float* Wq   = (const float*)d_in[9];
  const float* va   = (const float*)d_in[10];
  const float* Wa   = (const float*)d_in[11];
  const float* Wfc  = (const float*)d_in[12];
  const float* bfc  = (const float*)d_in[13];
  char* ws = (char*)d_ws;

  hipMemsetAsync(ws + OFF_SYNC, 0, 8192, stream);

  prep_elem<<<4096, 256, 0, stream>>>(ws, dec, h0, mem, embt, Wq, Wa, bk);
  prep_swz <<<432, 256, 0, stream>>>(ws, Wm, Wk, Uk, Wa);
  prep_wfc <<<dim3(133,16), 256, 0, stream>>>(ws, Wfc);

  // keys = memory @ Wm : [3840,512] f16
  gemm16<128,64,2,2,1><<<dim3(8,30), 256, 0, stream>>>(
      (const f16*)(ws+OFF_MEM16), 512, (const f16*)(ws+OFF_WMSWZ), 512,
      ws+OFF_KEYS, nullptr, 3840, 512, 3840, 512);
  // embW = embA @ WkTop + bk_perm : [1984,2048] f32 (perm cols)
  gemm16<128,64,2,2,0><<<dim3(32,16), 256, 0, stream>>>(
      (const f16*)(ws+OFF_EMBA), 320, (const f16*)(ws+OFF_WKTOP), 2048,
      ws+OFF_EMBW, (const float*)(ws+OFF_BKP), 1984, 320, 1984, 2048);
  // Wca = Wa @ WkAttn : [1024,2048] f32 (perm cols)
  gemm16<128,64,2,2,0><<<dim3(32,8), 256, 0, stream>>>(
      (const f16*)(ws+OFF_WA16), 512, (const f16*)(ws+OFF_WKATT), 2048,
      ws+OFF_WCA, nullptr, 1024, 512, 1024, 2048);
  build_wstar<<<256, 256, 0, stream>>>(ws, Uk);

  recur<<<64, 512, 0, stream>>>(ws, c0, va);

  // attn_all = Y @ Wa : [1984,512] f16
  gemm16<128,64,2,2,1><<<dim3(8,16), 256, 0, stream>>>(
      (const f16*)(ws+OFF_YALL), 1024, (const f16*)(ws+OFF_WASWZ), 512,
      ws+OFF_ATT16, nullptr, 1984, 1024, 1984, 512);
  // logits = attn_all @ Wfc + bfc -> d_out [b][t][vocab]
  gemm16<128,256,2,4,2><<<dim3(133,16), 512, 0, stream>>>(
      (const f16*)(ws+OFF_ATT16), 512, (const f16*)(ws+OFF_WFC), VOCP,
      d_out, bfc, 1984, 512, 1984, VOC);
}

// Round 6
// 890.195 us; speedup vs baseline: 2.3545x; 1.4164x over previous
//
#include <hip/hip_runtime.h>
#include <cstdint>
#include <cstddef>

typedef _Float16 f16;
typedef _Float16 f16x8 __attribute__((ext_vector_type(8)));
typedef _Float16 f16x2 __attribute__((ext_vector_type(2)));
typedef float    f32x4 __attribute__((ext_vector_type(4)));

#define DEV static __device__ __forceinline__

constexpr int TOUT = 31;
constexpr int VOC  = 34004;
constexpr int VOCP = 34048;

// ---------------- ws layout (bytes) ----------------
constexpr size_t OFF_SYNC  = 0;                                         // 8192 (64 flags @128B)
constexpr size_t OFF_MEM16 = 8192;                                      // [3840][512] f16
constexpr size_t OFF_WMSWZ = OFF_MEM16 + (size_t)3840*512*2;            // [16][512][32] f16
constexpr size_t OFF_KEYS  = OFF_WMSWZ + (size_t)16*512*32*2;           // [3840][512] f16
constexpr size_t OFF_EMBA  = OFF_KEYS  + (size_t)3840*512*2;            // [1984][320] f16 (prep-only)
constexpr size_t OFF_WKTOP = OFF_EMBA  + (size_t)1984*320*2;            // [10][2048][32] f16 (prep-only)
constexpr size_t OFF_EMBW  = OFF_WKTOP + (size_t)10*2048*32*2;          // [1984][2048] f32 (perm cols)
constexpr size_t OFF_WA16  = OFF_EMBW  + (size_t)1984*2048*4;           // [1024][512] f16 rowmajor
constexpr size_t OFF_WKATT = OFF_WA16  + (size_t)1024*512*2;            // [16][2048][32] f16 (perm)
constexpr size_t OFF_WCA   = OFF_WKATT + (size_t)16*2048*32*2;          // [1024][2048] f32 (perm cols)
constexpr size_t OFF_WSTAR = OFF_WCA   + (size_t)1024*2048*4;           // [32][2048][32] f16 (perm)
constexpr size_t OFF_UK16  = OFF_WSTAR + (size_t)32*2048*32*2;          // [16][2048][32] f16 (perm)
constexpr size_t OFF_WQSWZ = OFF_UK16  + (size_t)16*2048*32*2;          // [16 r][512 n][32 kk] f16
constexpr size_t OFF_WASWZ = OFF_WQSWZ + (size_t)512*512*2;             // [32][512][32] f16
constexpr size_t OFF_H016  = OFF_WASWZ + (size_t)32*512*32*2;           // [64][512] f16
constexpr size_t OFF_YALL  = OFF_H016  + (size_t)64*512*2;              // [31][64][1024] f16
constexpr size_t OFF_ATT16 = OFF_YALL  + (size_t)31*64*1024*2;          // [1984][512] f16
constexpr size_t OFF_BKP   = OFF_ATT16 + (size_t)1984*512*2;            // [2048] f32 (perm bk)
constexpr size_t OFF_WFC   = OFF_BKP   + 8192;                          // [16][34048][32] f16
// q_part scratch aliases prep-only EMBA/WKTOP (dead before recur): [64 srcblk][16 b][512] f32
constexpr size_t OFF_QP    = OFF_EMBA;                                  // 2 MB

// ---------------- helpers ----------------
DEV void gload16(const void* src, void* ldsbase /* wave-uniform */) {
  __builtin_amdgcn_global_load_lds(
      (const __attribute__((address_space(1))) unsigned int*)src,
      (__attribute__((address_space(3))) unsigned int*)ldsbase, 16, 0, 0);
}

DEV float sigm(float x)      { return 1.f / (1.f + expf(-x)); }
DEV float tanh_fast(float x) { float e = __expf(2.f*x); return 1.f - 2.f/(e+1.f); }

DEV uint32_t aload_u32(const uint32_t* p){ return __hip_atomic_load(p, __ATOMIC_RELAXED, __HIP_MEMORY_SCOPE_AGENT); }
DEV float    aload_f32(const float* p)   { return __hip_atomic_load(p, __ATOMIC_RELAXED, __HIP_MEMORY_SCOPE_AGENT); }
DEV void astore_u32(uint32_t* p, uint32_t v){ __hip_atomic_store(p, v, __ATOMIC_RELAXED, __HIP_MEMORY_SCOPE_AGENT); }
DEV void astore_f32(float* p, float v)      { __hip_atomic_store(p, v, __ATOMIC_RELAXED, __HIP_MEMORY_SCOPE_AGENT); }

DEV uint32_t pack16(f16 a, f16 b){ f16x2 v; v[0]=a; v[1]=b; return __builtin_bit_cast(uint32_t, v); }

// ---------------- prep: elementwise conversions ----------------
__global__ void prep_elem(char* ws, const int* dec, const float* h0,
                          const float* memory, const float* embt,
                          const float* Wa, const float* bk)
{
  f16* mem16 = (f16*)(ws+OFF_MEM16);
  f16* embA  = (f16*)(ws+OFF_EMBA);
  f16* wa16  = (f16*)(ws+OFF_WA16);
  f16* h016  = (f16*)(ws+OFF_H016);
  float* bkp = (float*)(ws+OFF_BKP);
  constexpr int E0=1966080, E1=E0+634880, E2=E1+524288, E3=E2+32768, E4=E3+2048;
  for (int i = blockIdx.x*256 + threadIdx.x; i < E4; i += gridDim.x*256) {
    if (i < E0) { mem16[i] = (f16)memory[i]; }
    else if (i < E1) { int j=i-E0; int r=j/320, k=j-r*320; int t=r>>6, b=r&63;
      int tok = dec[b*TOUT+t];
      embA[j] = (k<300) ? (f16)embt[(size_t)tok*300+k] : (f16)0.f; }
    else if (i < E2) { int j=i-E1; wa16[j] = (f16)Wa[j]; }
    else if (i < E3) { int j=i-E2; h016[j] = (f16)h0[j]; }
    else { int j=i-E3; bkp[j] = bk[(j>>2) + (j&3)*512]; }
  }
}

// ---------------- prep: swizzled B-layouts [K/32][N][32] ----------------
__global__ void prep_swz(char* ws, const float* Wm, const float* Wk, const float* Uk,
                         const float* Wa, const float* Wq)
{
  int tg = blockIdx.x*256 + threadIdx.x;
  constexpr int S0=8192, S1=S0+20480, S2=S1+32768, S3=S2+32768, S4=S3+16384, S5=S4+8192;
  if (tg >= S5) return;
  f16 buf[32];
  f16* dst;
  if (tg < S0) {                       // Wm -> [16][512][32]
    int kt=tg>>9, n=tg&511;
    #pragma unroll
    for (int kk=0;kk<32;kk++) buf[kk] = (f16)Wm[(size_t)(kt*32+kk)*512 + n];
    dst = (f16*)(ws+OFF_WMSWZ) + (size_t)tg*32;
  } else if (tg < S1) {                // Wk rows 0..299 (pad->320), perm cols -> [10][2048][32]
    int j=tg-S0; int kt=j>>11, np=j&2047; int col=(np>>2)+(np&3)*512;
    #pragma unroll
    for (int kk=0;kk<32;kk++){ int k=kt*32+kk;
      buf[kk] = (k<300) ? (f16)Wk[(size_t)k*2048+col] : (f16)0.f; }
    dst = (f16*)(ws+OFF_WKTOP) + (size_t)j*32;
  } else if (tg < S2) {                // Wk rows 300..811, perm -> [16][2048][32]
    int j=tg-S1; int kt=j>>11, np=j&2047; int col=(np>>2)+(np&3)*512;
    #pragma unroll
    for (int kk=0;kk<32;kk++) buf[kk] = (f16)Wk[(size_t)(300+kt*32+kk)*2048+col];
    dst = (f16*)(ws+OFF_WKATT) + (size_t)j*32;
  } else if (tg < S3) {                // Uk, perm -> [16][2048][32]
    int j=tg-S2; int kt=j>>11, np=j&2047; int col=(np>>2)+(np&3)*512;
    #pragma unroll
    for (int kk=0;kk<32;kk++) buf[kk] = (f16)Uk[(size_t)(kt*32+kk)*2048+col];
    dst = (f16*)(ws+OFF_UK16) + (size_t)j*32;
  } else if (tg < S4) {                // Wa -> [32][512][32]
    int j=tg-S3; int kt=j>>9, n=j&511;
    #pragma unroll
    for (int kk=0;kk<32;kk++) buf[kk] = (f16)Wa[(size_t)(kt*32+kk)*512 + n];
    dst = (f16*)(ws+OFF_WASWZ) + (size_t)j*32;
  } else {                             // Wq -> [16 r][512 n][32 kk], kk = u within slice
    int j=tg-S4; int rr=j>>9, n=j&511;
    #pragma unroll
    for (int kk=0;kk<32;kk++) buf[kk] = (f16)Wq[(size_t)(rr*32+kk)*512 + n];
    dst = (f16*)(ws+OFF_WQSWZ) + (size_t)j*32;
  }
  f16x8* d8 = (f16x8*)dst; f16x8* s8 = (f16x8*)buf;
  d8[0]=s8[0]; d8[1]=s8[1]; d8[2]=s8[2]; d8[3]=s8[3];
}

// ---------------- prep: Wfc -> [16][34048][32] f16 ----------------
__global__ void prep_wfc(char* ws, const float* Wfc)
{
  int n  = blockIdx.x*256 + threadIdx.x;   // 0..34047
  int kt = blockIdx.y;                      // 0..15
  f16 buf[32];
  #pragma unroll
  for (int kk=0;kk<32;kk++)
    buf[kk] = (n < VOC) ? (f16)Wfc[(size_t)(kt*32+kk)*VOC + n] : (f16)0.f;
  f16* dst = (f16*)(ws+OFF_WFC) + ((size_t)kt*VOCP + n)*32;
  f16x8* d8 = (f16x8*)dst; f16x8* s8 = (f16x8*)buf;
  d8[0]=s8[0]; d8[1]=s8[1]; d8[2]=s8[2]; d8[3]=s8[3];
}

// ---------------- build W* = Wca + [Uk;0] -> [32][2048][32] (perm) ----------------
__global__ void build_wstar(char* ws, const float* Uk)
{
  int tg = blockIdx.x*256 + threadIdx.x;   // 65536
  int kt = tg>>11, np = tg&2047;
  int col = (np>>2)+(np&3)*512;
  const float* wca = (const float*)(ws+OFF_WCA);
  f16 buf[32];
  #pragma unroll
  for (int kk=0;kk<32;kk++){
    int k = kt*32+kk;
    float v = wca[(size_t)k*2048 + np];
    if (k < 512) v += Uk[(size_t)k*2048 + col];
    buf[kk] = (f16)v;
  }
  f16* dst = (f16*)(ws+OFF_WSTAR) + (size_t)tg*32;
  f16x8* d8 = (f16x8*)dst; f16x8* s8 = (f16x8*)buf;
  d8[0]=s8[0]; d8[1]=s8[1]; d8[2]=s8[2]; d8[3]=s8[3];
}

// ---------------- generic fp16 MFMA GEMM (prologue/epilogue GEMMs) ----------------
template<int BM, int BN, int WR, int WC, int MODE>
__global__ __launch_bounds__(WR*WC*64, 1)
void gemm16(const f16* __restrict__ A, int lda,
            const f16* __restrict__ Bs, int Np,
            void* __restrict__ C, const float* __restrict__ bias,
            int M, int K, int Mreal, int Nreal)
{
  constexpr int NT  = WR*WC*64;
  constexpr int WTM = BM/WR, WTN = BN/WC, AM = WTM/16, AN = WTN/16;
  constexpr int NLA = BM*64/(NT*16), NLB = BN*64/(NT*16);
  __shared__ __align__(16) f16 sA[BM*32];
  __shared__ __align__(16) f16 sB[BN*32];
  const int tid = threadIdx.x, wave = tid>>6, lane = tid&63;
  const int lg = lane>>4, lr = lane&15;
  const int m0 = blockIdx.y*BM, n0 = blockIdx.x*BN;
  const int wm = (wave/WC)*WTM, wn = (wave%WC)*WTN;

  f32x4 acc[AM][AN] = {};

  int aoff[AM], boff[AN];
  #pragma unroll
  for (int i=0;i<AM;i++){ int row = wm+i*16+lr; aoff[i] = row*64 + (((lg + (row>>1))&3)<<4); }
  #pragma unroll
  for (int i=0;i<AN;i++){ int row = wn+i*16+lr; boff[i] = row*64 + (((lg + (row>>1))&3)<<4); }

  const int ksteps = K/32;
  for (int ks=0; ks<ksteps; ks++){
    const int k0 = ks*32;
    __syncthreads();
    #pragma unroll
    for (int i=0;i<NLA;i++){
      int p = i*NT + tid;
      int row = p>>2; int g = ((p&3) - (row>>1)) & 3;
      int gm = m0+row; if (gm > Mreal-1) gm = Mreal-1;
      gload16(A + (size_t)gm*lda + k0 + g*8, (char*)sA + (i*NT + wave*64)*16);
    }
    #pragma unroll
    for (int i=0;i<NLB;i++){
      int p = i*NT + tid;
      int row = p>>2; int g = ((p&3) - (row>>1)) & 3;
      gload16(Bs + ((size_t)(k0>>5)*Np + (n0+row))*32 + g*8, (char*)sB + (i*NT + wave*64)*16);
    }
    __syncthreads();
    f16x8 af[AM], bf[AN];
    #pragma unroll
    for (int i=0;i<AM;i++) af[i] = *(const f16x8*)((const char*)sA + aoff[i]);
    #pragma unroll
    for (int i=0;i<AN;i++) bf[i] = *(const f16x8*)((const char*)sB + boff[i]);
    #pragma unroll
    for (int i=0;i<AM;i++)
      #pragma unroll
      for (int j=0;j<AN;j++)
        acc[i][j] = __builtin_amdgcn_mfma_f32_16x16x32_f16(af[i], bf[j], acc[i][j], 0,0,0);
  }

  #pragma unroll
  for (int i=0;i<AM;i++)
    #pragma unroll
    for (int j=0;j<AN;j++){
      int n = n0 + wn + j*16 + lr;
      if (MODE == 2 && n >= Nreal) continue;
      float bb = 0.f;
      if (MODE != 1 && bias) bb = bias[n];
      #pragma unroll
      for (int r=0;r<4;r++){
        int m = m0 + wm + i*16 + lg*4 + r;
        if (m >= Mreal) continue;
        float v = acc[i][j][r] + bb;
        if (MODE == 0)      ((float*)C)[(size_t)m*Np + n] = v;
        else if (MODE == 1) ((f16*)C)[(size_t)m*Np + n] = (f16)v;
        else { int t = m>>6, b = m&63; ((float*)C)[((size_t)(b*TOUT+t))*VOC + n] = v; }
      }
    }
}

// ---------------- cluster barrier: flag array, sc1 relaxed (R3-proven) ----------------
DEV void cbar(uint32_t* flags, int cbase, int r, int tid, uint32_t target)
{
  asm volatile("s_waitcnt vmcnt(0)" ::: "memory");
  __syncthreads();
  if (tid == 0)
    astore_u32(flags + (size_t)(cbase + r)*32, target);
  if (tid < 16) {
    while (aload_u32(flags + (size_t)(cbase + tid)*32) < target)
      __builtin_amdgcn_s_sleep(1);
  }
  __syncthreads();
}

// ---------------- P1 inner: one 16(b)x16(col) tile over K, 8-deep B prefetch ----------------
template<int KS>
DEV f32x4 p1_mfma(const f16* __restrict__ Bs, const char* ylb, int col, int kg, int lr)
{
  f16x8 B[8];
  #pragma unroll
  for (int i=0;i<8;i++)
    B[i] = *(const f16x8*)(Bs + (((size_t)i*2048 + col)<<5) + kg*8);
  f32x4 acc = {};
  #pragma unroll
  for (int ks=0; ks<KS; ks+=8) {
    #pragma unroll
    for (int i=0;i<8;i++) {
      f16x8 a = *(const f16x8*)(ylb + lr*2064 + (ks+i)*64 + kg*16);
      acc = __builtin_amdgcn_mfma_f32_16x16x32_f16(a, B[i], acc, 0,0,0);
      int nk = ks+8+i;
      if (nk < KS)
        B[i] = *(const f16x8*)(Bs + (((size_t)nk*2048 + col)<<5) + kg*8);
    }
  }
  return acc;
}

// ---------------- persistent recurrence: 4 clusters x 16 blocks ----------------
// Block r of cluster c owns: P1 perm-cols [128r,128r+128) = units [32r,32r+32)
// (z never leaves the block: gates/c/h computed locally); q_part via MFMA;
// P2 owns batch 16c+r (q-sum, scores, softmax, ctx).
__global__ __launch_bounds__(512, 1)
void recur(char* ws, const float* __restrict__ c0, const float* __restrict__ v_att)
{
  const int blk = blockIdx.x, tid = threadIdx.x;
  const int wave = tid>>6, lane = tid&63;
  const int lr = lane&15, kg = lane>>4;
  const int clus = blk>>4, r = blk&15;
  const int cbase = clus<<4;
  const int bown = cbase + r;
  const int n0 = r*128;                 // perm-col base (units [32r,32r+32) x 4 gates)

  uint32_t* flags = (uint32_t*)(ws+OFF_SYNC);
  float* qp = (float*)(ws+OFF_QP);
  const f16* wstar = (const f16*)(ws+OFF_WSTAR);
  const f16* uk16  = (const f16*)(ws+OFF_UK16);
  const f16* wqswz = (const f16*)(ws+OFF_WQSWZ);
  const f16* keys16= (const f16*)(ws+OFF_KEYS);
  const f16* mem16 = (const f16*)(ws+OFF_MEM16);
  const float* embw= (const float*)(ws+OFF_EMBW);

  __shared__ __align__(16) char  yl[16*2064];    // 16 batches x 1024 f16 (stride 2064B)
  __shared__ __align__(16) float zl[16*132];     // z slice [16 b][128 col] (+pad)
  __shared__ __align__(16) float c_sl[16*32];    // persistent c-state slice
  __shared__ __align__(16) f16   h_sl[16*32];    // h slice [16 b][32 u]
  __shared__ __align__(16) float q_l[512];
  __shared__ __align__(16) float v_l[512];
  __shared__ __align__(16) f16   cx16_l[512];
  __shared__ __align__(16) float sc_l[64];

  v_l[tid] = v_att[tid];
  { int b = tid>>5, uu = tid&31;
    c_sl[b*32+uu] = c0[(size_t)(cbase+b)*512 + r*32 + uu]; }

  for (int t=0; t<TOUT; t++){
    // ---------- gather y(t-1) for the cluster's 16 batches (sc1) ----------
    {
      const uint32_t* ysrc; int rw;
      if (t == 0) { ysrc = (const uint32_t*)(ws+OFF_H016); rw = 256; }
      else        { ysrc = (const uint32_t*)(ws+OFF_YALL + (size_t)(t-1)*64*1024*2); rw = 512; }
      if (tid < rw) {
        uint32_t g[16];
        #pragma unroll
        for (int q=0;q<16;q++) g[q] = aload_u32(ysrc + (size_t)(cbase+q)*rw + tid);
        #pragma unroll
        for (int q=0;q<16;q++) *(uint32_t*)(yl + q*2064 + tid*4) = g[q];
      }
      __syncthreads();
    }

    // ---------- P1: z[16 b][own 128 cols] via MFMA, kept in LDS ----------
    {
      const int col = n0 + wave*16 + lr;
      f32x4 acc = (t==0) ? p1_mfma<16>(uk16,  yl, col, kg, lr)
                         : p1_mfma<32>(wstar, yl, col, kg, lr);
      #pragma unroll
      for (int rr=0;rr<4;rr++)
        zl[(kg*4+rr)*132 + wave*16 + lr] = acc[rr];
    }
    __syncthreads();

    // ---------- gates + c/h update (local; thread = (batch b, unit uu)) ----------
    {
      const int b = tid>>5, uu = tid&31;
      f32x4 zz = *(const f32x4*)(zl + b*132 + uu*4);
      f32x4 e  = *(const f32x4*)(embw + ((size_t)(t*64+cbase+b))*2048 + n0 + uu*4);
      float ig = sigm(zz[0]+e[0]), fg = sigm(zz[1]+e[1]);
      float gg = tanhf(zz[2]+e[2]), og = sigm(zz[3]+e[3]);
      float cn = fg*c_sl[b*32+uu] + ig*gg;
      c_sl[b*32+uu] = cn;
      h_sl[b*32+uu] = (f16)(og * tanhf(cn));
    }
    __syncthreads();

    // ---------- publish h slices to y_all; q_part = h_slice @ Wq_slice (MFMA) ----------
    uint32_t* yt = (uint32_t*)(ws+OFF_YALL) + (size_t)t*64*512;
    if (tid < 256) {
      int b = tid>>4, j = tid&15;
      astore_u32(yt + (size_t)(cbase+b)*512 + r*16 + j,
                 pack16(h_sl[b*32+2*j], h_sl[b*32+2*j+1]));
    }
    {
      f16x8 a = *(const f16x8*)(h_sl + lr*32 + kg*8);
      #pragma unroll
      for (int j=0;j<4;j++){
        int n = wave*64 + j*16 + lr;
        f16x8 bf = *(const f16x8*)(wqswz + ((size_t)(r*512 + n))*32 + kg*8);
        f32x4 aq = __builtin_amdgcn_mfma_f32_16x16x32_f16(a, bf, (f32x4){0.f,0.f,0.f,0.f}, 0,0,0);
        #pragma unroll
        for (int rr=0;rr<4;rr++)
          astore_f32(qp + ((size_t)blk*16 + kg*4+rr)*512 + n, aq[rr]);
      }
    }
    cbar(flags, cbase, r, tid, 2*t+1);

    // ---------- P2 (own batch): q-sum -> scores -> softmax -> ctx ----------
    {
      float pv[16];
      #pragma unroll
      for (int s=0;s<16;s++)
        pv[s] = aload_f32(qp + ((size_t)(cbase+s)*16 + r)*512 + tid);
      float qs = 0.f;
      #pragma unroll
      for (int s=0;s<16;s++) qs += pv[s];
      q_l[tid] = qs;
    }
    __syncthreads();

    for (int i = wave; i < 60; i += 8){
      const f16* krow = keys16 + ((size_t)(bown*60+i))*512;
      float p = 0.f;
      #pragma unroll
      for (int s=0;s<8;s++){
        int u = lane + s*64;
        p += tanh_fast((float)krow[u] + q_l[u]) * v_l[u];
      }
      #pragma unroll
      for (int m=32;m;m>>=1) p += __shfl_xor(p, m, 64);
      if (lane == 0) sc_l[i] = p;
    }
    __syncthreads();
    if (wave == 0){
      float s = (lane < 60) ? sc_l[lane] : -1e30f;
      float mx = s;
      #pragma unroll
      for (int m=32;m;m>>=1) mx = fmaxf(mx, __shfl_xor(mx, m, 64));
      float ev = (lane < 60) ? __expf(s - mx) : 0.f;
      float sum = ev;
      #pragma unroll
      for (int m=32;m;m>>=1) sum += __shfl_xor(sum, m, 64);
      if (lane < 60) sc_l[lane] = ev / sum;
    }
    __syncthreads();
    {
      float cx = 0.f;
      const f16* mrow = mem16 + ((size_t)bown*60)*512 + tid;
      #pragma unroll 4
      for (int i=0;i<60;i++) cx += sc_l[i] * (float)mrow[(size_t)i*512];
      cx16_l[tid] = (f16)cx;
    }
    __syncthreads();
    if (tid < 256)
      astore_u32(yt + (size_t)bown*512 + 256 + tid,
                 pack16(cx16_l[2*tid], cx16_l[2*tid+1]));
    cbar(flags, cbase, r, tid, 2*t+2);
  }
}

// ---------------- host ----------------
extern "C" void kernel_launch(void* const* d_in, const int* in_sizes, int n_in,
                              void* d_out, int out_size, void* d_ws, size_t ws_size,
                              hipStream_t stream)
{
  const int*   dec  = (const int*)  d_in[0];
  const float* h0   = (const float*)d_in[1];
  const float* c0   = (const float*)d_in[2];
  const float* mem  = (const float*)d_in[3];
  const float* embt = (const float*)d_in[4];
  const float* Wk   = (const float*)d_in[5];
  const float* Uk   = (const float*)d_in[6];
  const float* bk   = (const float*)d_in[7];
  const float* Wm   = (const float*)d_in[8];
  const float* Wq   = (const float*)d_in[9];
  const float* va   = (const float*)d_in[10];
  const float* Wa   = (const float*)d_in[11];
  const float* Wfc  = (const float*)d_in[12];
  const float* bfc  = (const float*)d_in[13];
  char* ws = (char*)d_ws;

  hipMemsetAsync(ws + OFF_SYNC, 0, 8192, stream);

  prep_elem<<<4096, 256, 0, stream>>>(ws, dec, h0, mem, embt, Wa, bk);
  prep_swz <<<464, 256, 0, stream>>>(ws, Wm, Wk, Uk, Wa, Wq);
  prep_wfc <<<dim3(133,16), 256, 0, stream>>>(ws, Wfc);

  // keys = memory @ Wm : [3840,512] f16
  gemm16<128,64,2,2,1><<<dim3(8,30), 256, 0, stream>>>(
      (const f16*)(ws+OFF_MEM16), 512, (const f16*)(ws+OFF_WMSWZ), 512,
      ws+OFF_KEYS, nullptr, 3840, 512, 3840, 512);
  // embW = embA @ WkTop + bk_perm : [1984,2048] f32 (perm cols)
  gemm16<128,64,2,2,0><<<dim3(32,16), 256, 0, stream>>>(
      (const f16*)(ws+OFF_EMBA), 320, (const f16*)(ws+OFF_WKTOP), 2048,
      ws+OFF_EMBW, (const float*)(ws+OFF_BKP), 1984, 320, 1984, 2048);
  // Wca = Wa @ WkAttn : [1024,2048] f32 (perm cols)
  gemm16<128,64,2,2,0><<<dim3(32,8), 256, 0, stream>>>(
      (const f16*)(ws+OFF_WA16), 512, (const f16*)(ws+OFF_WKATT), 2048,
      ws+OFF_WCA, nullptr, 1024, 512, 1024, 2048);
  build_wstar<<<256, 256, 0, stream>>>(ws, Uk);

  recur<<<64, 512, 0, stream>>>(ws, c0, va);

  // attn_all = Y @ Wa : [1984,512] f16
  gemm16<128,64,2,2,1><<<dim3(8,16), 256, 0, stream>>>(
      (const f16*)(ws+OFF_YALL), 1024, (const f16*)(ws+OFF_WASWZ), 512,
      ws+OFF_ATT16, nullptr, 1984, 1024, 1984, 512);
  // logits = attn_all @ Wfc + bfc -> d_out [b][t][vocab]
  gemm16<128,256,2,4,2><<<dim3(133,16), 512, 0, stream>>>(
      (const f16*)(ws+OFF_ATT16), 512, (const f16*)(ws+OFF_WFC), VOCP,
      d_out, bfc, 1984, 512, 1984, VOC);
}

// Round 7
// 836.573 us; speedup vs baseline: 2.5054x; 1.0641x over previous
//
#include <hip/hip_runtime.h>
#include <cstdint>
#include <cstddef>

typedef _Float16 f16;
typedef _Float16 f16x8 __attribute__((ext_vector_type(8)));
typedef _Float16 f16x2 __attribute__((ext_vector_type(2)));
typedef float    f32x4 __attribute__((ext_vector_type(4)));
typedef uint32_t u32x4 __attribute__((ext_vector_type(4)));

#define DEV static __device__ __forceinline__

constexpr int TOUT = 31;
constexpr int VOC  = 34004;
constexpr int VOCP = 34048;

// ---------------- ws layout (bytes) ----------------
constexpr size_t OFF_SYNC  = 0;                                         // 8192 (64 flags @128B)
constexpr size_t OFF_MEM16 = 8192;                                      // [3840][512] f16
constexpr size_t OFF_WMSWZ = OFF_MEM16 + (size_t)3840*512*2;            // [16][512][32] f16
constexpr size_t OFF_KEYS  = OFF_WMSWZ + (size_t)16*512*32*2;           // [3840][512] f16
constexpr size_t OFF_EMBA  = OFF_KEYS  + (size_t)3840*512*2;            // [1984][320] f16 (prep-only)
constexpr size_t OFF_WKTOP = OFF_EMBA  + (size_t)1984*320*2;            // [10][2048][32] f16 (prep-only)
constexpr size_t OFF_EMBW  = OFF_WKTOP + (size_t)10*2048*32*2;          // [1984][2048] f32 (perm cols)
constexpr size_t OFF_WA16  = OFF_EMBW  + (size_t)1984*2048*4;           // [1024][512] f16 rowmajor
constexpr size_t OFF_WKATT = OFF_WA16  + (size_t)1024*512*2;            // [16][2048][32] f16 (perm)
constexpr size_t OFF_WCA   = OFF_WKATT + (size_t)16*2048*32*2;          // [1024][2048] f32 (perm cols)
constexpr size_t OFF_WSTAR = OFF_WCA   + (size_t)1024*2048*4;           // [32][2048][32] f16 (perm)
constexpr size_t OFF_UK16  = OFF_WSTAR + (size_t)32*2048*32*2;          // [16][2048][32] f16 (perm)
constexpr size_t OFF_WQSWZ = OFF_UK16  + (size_t)16*2048*32*2;          // [16 r][512 n][32 kk] f16
constexpr size_t OFF_WASWZ = OFF_WQSWZ + (size_t)512*512*2;             // [32][512][32] f16
constexpr size_t OFF_H016  = OFF_WASWZ + (size_t)32*512*32*2;           // [64][512] f16
constexpr size_t OFF_YALL  = OFF_H016  + (size_t)64*512*2;              // [31][64][1024] f16
constexpr size_t OFF_ATT16 = OFF_YALL  + (size_t)31*64*1024*2;          // [1984][512] f16
constexpr size_t OFF_BKP   = OFF_ATT16 + (size_t)1984*512*2;            // [2048] f32 (perm bk)
constexpr size_t OFF_WFC   = OFF_BKP   + 8192;                          // [16][34048][32] f16
// q_part scratch aliases prep-only EMBA/WKTOP: [64 blk][16 b][512] f32 = 2 MB
constexpr size_t OFF_QP    = OFF_EMBA;

// ---------------- helpers ----------------
DEV void gload16(const void* src, void* ldsbase /* wave-uniform */) {
  __builtin_amdgcn_global_load_lds(
      (const __attribute__((address_space(1))) unsigned int*)src,
      (__attribute__((address_space(3))) unsigned int*)ldsbase, 16, 0, 0);
}

DEV float sigm(float x)      { return 1.f / (1.f + expf(-x)); }
DEV float tanh_fast(float x) { float e = __expf(2.f*x); return 1.f - 2.f/(e+1.f); }

DEV uint32_t aload_u32(const uint32_t* p){ return __hip_atomic_load(p, __ATOMIC_RELAXED, __HIP_MEMORY_SCOPE_AGENT); }
DEV void astore_u32(uint32_t* p, uint32_t v){ __hip_atomic_store(p, v, __ATOMIC_RELAXED, __HIP_MEMORY_SCOPE_AGENT); }

// wide agent-scope (sc1) transport — same coherence bit the relaxed agent atomics
// compile to; non-atomic width is fine (drained by vmcnt(0) before flag publish)
DEV void ld16_sc1(const void* p, u32x4& d){
  asm volatile("global_load_dwordx4 %0, %1, off sc1" : "=v"(d) : "v"(p));
}
DEV void st16_sc1(void* p, u32x4 v){
  asm volatile("global_store_dwordx4 %0, %1, off sc1" :: "v"(p), "v"(v) : "memory");
}
DEV void vwait(){ asm volatile("s_waitcnt vmcnt(0)" ::: "memory"); }

// ---------------- prep: elementwise conversions ----------------
__global__ void prep_elem(char* ws, const int* dec, const float* h0,
                          const float* memory, const float* embt,
                          const float* Wa, const float* bk)
{
  f16* mem16 = (f16*)(ws+OFF_MEM16);
  f16* embA  = (f16*)(ws+OFF_EMBA);
  f16* wa16  = (f16*)(ws+OFF_WA16);
  f16* h016  = (f16*)(ws+OFF_H016);
  float* bkp = (float*)(ws+OFF_BKP);
  constexpr int E0=1966080, E1=E0+634880, E2=E1+524288, E3=E2+32768, E4=E3+2048;
  for (int i = blockIdx.x*256 + threadIdx.x; i < E4; i += gridDim.x*256) {
    if (i < E0) { mem16[i] = (f16)memory[i]; }
    else if (i < E1) { int j=i-E0; int r=j/320, k=j-r*320; int t=r>>6, b=r&63;
      int tok = dec[b*TOUT+t];
      embA[j] = (k<300) ? (f16)embt[(size_t)tok*300+k] : (f16)0.f; }
    else if (i < E2) { int j=i-E1; wa16[j] = (f16)Wa[j]; }
    else if (i < E3) { int j=i-E2; h016[j] = (f16)h0[j]; }
    else { int j=i-E3; bkp[j] = bk[(j>>2) + (j&3)*512]; }
  }
}

// ---------------- prep: swizzled B-layouts [K/32][N][32] ----------------
__global__ void prep_swz(char* ws, const float* Wm, const float* Wk, const float* Uk,
                         const float* Wa, const float* Wq)
{
  int tg = blockIdx.x*256 + threadIdx.x;
  constexpr int S0=8192, S1=S0+20480, S2=S1+32768, S3=S2+32768, S4=S3+16384, S5=S4+8192;
  if (tg >= S5) return;
  f16 buf[32];
  f16* dst;
  if (tg < S0) {                       // Wm -> [16][512][32]
    int kt=tg>>9, n=tg&511;
    #pragma unroll
    for (int kk=0;kk<32;kk++) buf[kk] = (f16)Wm[(size_t)(kt*32+kk)*512 + n];
    dst = (f16*)(ws+OFF_WMSWZ) + (size_t)tg*32;
  } else if (tg < S1) {                // Wk rows 0..299 (pad->320), perm cols -> [10][2048][32]
    int j=tg-S0; int kt=j>>11, np=j&2047; int col=(np>>2)+(np&3)*512;
    #pragma unroll
    for (int kk=0;kk<32;kk++){ int k=kt*32+kk;
      buf[kk] = (k<300) ? (f16)Wk[(size_t)k*2048+col] : (f16)0.f; }
    dst = (f16*)(ws+OFF_WKTOP) + (size_t)j*32;
  } else if (tg < S2) {                // Wk rows 300..811, perm -> [16][2048][32]
    int j=tg-S1; int kt=j>>11, np=j&2047; int col=(np>>2)+(np&3)*512;
    #pragma unroll
    for (int kk=0;kk<32;kk++) buf[kk] = (f16)Wk[(size_t)(300+kt*32+kk)*2048+col];
    dst = (f16*)(ws+OFF_WKATT) + (size_t)j*32;
  } else if (tg < S3) {                // Uk, perm -> [16][2048][32]
    int j=tg-S2; int kt=j>>11, np=j&2047; int col=(np>>2)+(np&3)*512;
    #pragma unroll
    for (int kk=0;kk<32;kk++) buf[kk] = (f16)Uk[(size_t)(kt*32+kk)*2048+col];
    dst = (f16*)(ws+OFF_UK16) + (size_t)j*32;
  } else if (tg < S4) {                // Wa -> [32][512][32]
    int j=tg-S3; int kt=j>>9, n=j&511;
    #pragma unroll
    for (int kk=0;kk<32;kk++) buf[kk] = (f16)Wa[(size_t)(kt*32+kk)*512 + n];
    dst = (f16*)(ws+OFF_WASWZ) + (size_t)j*32;
  } else {                             // Wq -> [16 r][512 n][32 kk]
    int j=tg-S4; int rr=j>>9, n=j&511;
    #pragma unroll
    for (int kk=0;kk<32;kk++) buf[kk] = (f16)Wq[(size_t)(rr*32+kk)*512 + n];
    dst = (f16*)(ws+OFF_WQSWZ) + (size_t)j*32;
  }
  f16x8* d8 = (f16x8*)dst; f16x8* s8 = (f16x8*)buf;
  d8[0]=s8[0]; d8[1]=s8[1]; d8[2]=s8[2]; d8[3]=s8[3];
}

// ---------------- prep: Wfc -> [16][34048][32] f16 ----------------
__global__ void prep_wfc(char* ws, const float* Wfc)
{
  int n  = blockIdx.x*256 + threadIdx.x;
  int kt = blockIdx.y;
  f16 buf[32];
  #pragma unroll
  for (int kk=0;kk<32;kk++)
    buf[kk] = (n < VOC) ? (f16)Wfc[(size_t)(kt*32+kk)*VOC + n] : (f16)0.f;
  f16* dst = (f16*)(ws+OFF_WFC) + ((size_t)kt*VOCP + n)*32;
  f16x8* d8 = (f16x8*)dst; f16x8* s8 = (f16x8*)buf;
  d8[0]=s8[0]; d8[1]=s8[1]; d8[2]=s8[2]; d8[3]=s8[3];
}

// ---------------- build W* = Wca + [Uk;0] -> [32][2048][32] (perm) ----------------
__global__ void build_wstar(char* ws, const float* Uk)
{
  int tg = blockIdx.x*256 + threadIdx.x;
  int kt = tg>>11, np = tg&2047;
  int col = (np>>2)+(np&3)*512;
  const float* wca = (const float*)(ws+OFF_WCA);
  f16 buf[32];
  #pragma unroll
  for (int kk=0;kk<32;kk++){
    int k = kt*32+kk;
    float v = wca[(size_t)k*2048 + np];
    if (k < 512) v += Uk[(size_t)k*2048 + col];
    buf[kk] = (f16)v;
  }
  f16* dst = (f16*)(ws+OFF_WSTAR) + (size_t)tg*32;
  f16x8* d8 = (f16x8*)dst; f16x8* s8 = (f16x8*)buf;
  d8[0]=s8[0]; d8[1]=s8[1]; d8[2]=s8[2]; d8[3]=s8[3];
}

// ---------------- generic fp16 MFMA GEMM (prologue/epilogue GEMMs) ----------------
template<int BM, int BN, int WR, int WC, int MODE>
__global__ __launch_bounds__(WR*WC*64, 1)
void gemm16(const f16* __restrict__ A, int lda,
            const f16* __restrict__ Bs, int Np,
            void* __restrict__ C, const float* __restrict__ bias,
            int M, int K, int Mreal, int Nreal)
{
  constexpr int NT  = WR*WC*64;
  constexpr int WTM = BM/WR, WTN = BN/WC, AM = WTM/16, AN = WTN/16;
  constexpr int NLA = BM*64/(NT*16), NLB = BN*64/(NT*16);
  __shared__ __align__(16) f16 sA[BM*32];
  __shared__ __align__(16) f16 sB[BN*32];
  const int tid = threadIdx.x, wave = tid>>6, lane = tid&63;
  const int lg = lane>>4, lr = lane&15;
  const int m0 = blockIdx.y*BM, n0 = blockIdx.x*BN;
  const int wm = (wave/WC)*WTM, wn = (wave%WC)*WTN;

  f32x4 acc[AM][AN] = {};

  int aoff[AM], boff[AN];
  #pragma unroll
  for (int i=0;i<AM;i++){ int row = wm+i*16+lr; aoff[i] = row*64 + (((lg + (row>>1))&3)<<4); }
  #pragma unroll
  for (int i=0;i<AN;i++){ int row = wn+i*16+lr; boff[i] = row*64 + (((lg + (row>>1))&3)<<4); }

  const int ksteps = K/32;
  for (int ks=0; ks<ksteps; ks++){
    const int k0 = ks*32;
    __syncthreads();
    #pragma unroll
    for (int i=0;i<NLA;i++){
      int p = i*NT + tid;
      int row = p>>2; int g = ((p&3) - (row>>1)) & 3;
      int gm = m0+row; if (gm > Mreal-1) gm = Mreal-1;
      gload16(A + (size_t)gm*lda + k0 + g*8, (char*)sA + (i*NT + wave*64)*16);
    }
    #pragma unroll
    for (int i=0;i<NLB;i++){
      int p = i*NT + tid;
      int row = p>>2; int g = ((p&3) - (row>>1)) & 3;
      gload16(Bs + ((size_t)(k0>>5)*Np + (n0+row))*32 + g*8, (char*)sB + (i*NT + wave*64)*16);
    }
    __syncthreads();
    f16x8 af[AM], bf[AN];
    #pragma unroll
    for (int i=0;i<AM;i++) af[i] = *(const f16x8*)((const char*)sA + aoff[i]);
    #pragma unroll
    for (int i=0;i<AN;i++) bf[i] = *(const f16x8*)((const char*)sB + boff[i]);
    #pragma unroll
    for (int i=0;i<AM;i++)
      #pragma unroll
      for (int j=0;j<AN;j++)
        acc[i][j] = __builtin_amdgcn_mfma_f32_16x16x32_f16(af[i], bf[j], acc[i][j], 0,0,0);
  }

  #pragma unroll
  for (int i=0;i<AM;i++)
    #pragma unroll
    for (int j=0;j<AN;j++){
      int n = n0 + wn + j*16 + lr;
      if (MODE == 2 && n >= Nreal) continue;
      float bb = 0.f;
      if (MODE != 1 && bias) bb = bias[n];
      #pragma unroll
      for (int r=0;r<4;r++){
        int m = m0 + wm + i*16 + lg*4 + r;
        if (m >= Mreal) continue;
        float v = acc[i][j][r] + bb;
        if (MODE == 0)      ((float*)C)[(size_t)m*Np + n] = v;
        else if (MODE == 1) ((f16*)C)[(size_t)m*Np + n] = (f16)v;
        else { int t = m>>6, b = m&63; ((float*)C)[((size_t)(b*TOUT+t))*VOC + n] = v; }
      }
    }
}

// ---------------- cluster barrier: sc1 flag array (R3/R6-proven) ----------------
DEV void cbar(uint32_t* flags, int cbase, int r, int tid, uint32_t target)
{
  vwait();
  __syncthreads();
  if (tid == 0)
    astore_u32(flags + (size_t)(cbase + r)*32, target);
  if (tid < 16) {
    while (aload_u32(flags + (size_t)(cbase + tid)*32) < target)
      __builtin_amdgcn_s_sleep(1);
  }
  __syncthreads();
}

// ---------------- P1 inner: one 16(b)x16(col) tile over K, 8-deep B prefetch ----------------
template<int KS>
DEV f32x4 p1_mfma(const f16* __restrict__ Bs, const char* ylb, int col, int kg, int lr)
{
  f16x8 B[8];
  #pragma unroll
  for (int i=0;i<8;i++)
    B[i] = *(const f16x8*)(Bs + (((size_t)i*2048 + col)<<5) + kg*8);
  f32x4 acc = {};
  #pragma unroll
  for (int ks=0; ks<KS; ks+=8) {
    #pragma unroll
    for (int i=0;i<8;i++) {
      f16x8 a = *(const f16x8*)(ylb + lr*2064 + (ks+i)*64 + kg*16);
      acc = __builtin_amdgcn_mfma_f32_16x16x32_f16(a, B[i], acc, 0,0,0);
      int nk = ks+8+i;
      if (nk < KS)
        B[i] = *(const f16x8*)(Bs + (((size_t)nk*2048 + col)<<5) + kg*8);
    }
  }
  return acc;
}

// ---------------- persistent recurrence: 4 clusters x 16 blocks ----------------
__global__ __launch_bounds__(512, 1)
void recur(char* ws, const float* __restrict__ c0, const float* __restrict__ v_att)
{
  const int blk = blockIdx.x, tid = threadIdx.x;
  const int wave = tid>>6, lane = tid&63;
  const int lr = lane&15, kg = lane>>4;
  const int clus = blk>>4, r = blk&15;
  const int cbase = clus<<4;
  const int bown = cbase + r;
  const int n0 = r*128;

  uint32_t* flags = (uint32_t*)(ws+OFF_SYNC);
  char* qpg = (char*)(ws+OFF_QP);
  const f16* wstar = (const f16*)(ws+OFF_WSTAR);
  const f16* uk16  = (const f16*)(ws+OFF_UK16);
  const f16* wqswz = (const f16*)(ws+OFF_WQSWZ);
  const f16* keys16= (const f16*)(ws+OFF_KEYS);
  const f16* mem16 = (const f16*)(ws+OFF_MEM16);
  const float* embw= (const float*)(ws+OFF_EMBW);

  __shared__ __align__(16) char  ybuf[33024];   // y tiles (16 x 2064) / qp stage+gather [16][512] f32
  __shared__ __align__(16) float zl[16*132];
  __shared__ __align__(16) float c_sl[512];     // [16 b][32 u]
  __shared__ __align__(16) f16   h_sl[512];     // [16 b][32 u]
  __shared__ __align__(16) float q_l[512];
  __shared__ __align__(16) float v_l[512];
  __shared__ __align__(16) f16   cx16_l[512];
  __shared__ __align__(16) float sc_l[64];
  __shared__ __align__(16) f16   mem_lds[60*512];  // own batch raw memory (loop-invariant)

  v_l[tid] = v_att[tid];
  { int b = tid>>5, uu = tid&31;
    c_sl[tid] = c0[(size_t)(cbase+b)*512 + r*32 + uu]; }

  // stage own batch's memory rows into LDS once (3840 x 16B chunks)
  {
    const char* msrc = (const char*)(mem16 + (size_t)bown*60*512);
    #pragma unroll
    for (int i=0;i<8;i++){
      int cb = i*512 + wave*64;
      if (cb < 3840)
        gload16(msrc + ((size_t)cb + lane)*16, (char*)mem_lds + (size_t)cb*16);
    }
  }

  for (int t=0; t<TOUT; t++){
    // ---------- A: gather y(t-1) for the cluster's 16 batches (wide sc1) ----------
    {
      const char* ysrc; int rsh;
      if (t == 0) { ysrc = ws+OFF_H016; rsh = 6; }                            // 1KB rows
      else        { ysrc = ws+OFF_YALL + (size_t)(t-1)*64*2048; rsh = 7; }    // 2KB rows
      const int npass = (16 << rsh) >> 9;   // 2 or 4
      u32x4 g[4];
      #pragma unroll
      for (int p=0;p<4;p++){
        if (p < npass){
          int cid = p*512 + tid, row = cid>>rsh, off = cid & ((1<<rsh)-1);
          ld16_sc1(ysrc + ((size_t)(cbase+row) << (rsh+4)) + off*16, g[p]);
        }
      }
      vwait();
      #pragma unroll
      for (int p=0;p<4;p++){
        if (p < npass){
          int cid = p*512 + tid, row = cid>>rsh, off = cid & ((1<<rsh)-1);
          *(u32x4*)(ybuf + row*2064 + off*16) = g[p];
        }
      }
      __syncthreads();
    }

    // ---------- B: P1 z[16 b][own 128 cols] via MFMA, kept in LDS ----------
    {
      const int col = n0 + wave*16 + lr;
      f32x4 acc = (t==0) ? p1_mfma<16>(uk16,  ybuf, col, kg, lr)
                         : p1_mfma<32>(wstar, ybuf, col, kg, lr);
      #pragma unroll
      for (int rr=0;rr<4;rr++)
        zl[(kg*4+rr)*132 + wave*16 + lr] = acc[rr];
    }
    __syncthreads();

    // ---------- gates + c/h update ----------
    {
      const int b = tid>>5, uu = tid&31;
      f32x4 zz = *(const f32x4*)(zl + b*132 + uu*4);
      f32x4 e  = *(const f32x4*)(embw + ((size_t)(t*64+cbase+b))*2048 + n0 + uu*4);
      float ig = sigm(zz[0]+e[0]), fg = sigm(zz[1]+e[1]);
      float gg = tanhf(zz[2]+e[2]), og = sigm(zz[3]+e[3]);
      float cn = fg*c_sl[tid] + ig*gg;
      c_sl[tid] = cn;
      h_sl[tid] = (f16)(og * tanhf(cn));
    }
    __syncthreads();

    // ---------- C: publish h slices (wide sc1) ----------
    char* yt = (char*)(ws+OFF_YALL) + (size_t)t*64*2048;
    if (tid < 64){
      int b = tid>>2, off = tid&3;
      u32x4 v = *(const u32x4*)((const char*)h_sl + b*64 + off*16);
      st16_sc1(yt + (size_t)(cbase+b)*2048 + r*64 + off*16, v);
    }

    // ---------- D: q_part = h_slice @ Wq_slice (MFMA) -> LDS stage ----------
    {
      float* qs = (float*)ybuf;      // ybuf dead after P1
      f16x8 a = *(const f16x8*)(h_sl + lr*32 + kg*8);
      #pragma unroll
      for (int j=0;j<4;j++){
        int n = wave*64 + j*16 + lr;
        f16x8 bf = *(const f16x8*)(wqswz + ((size_t)(r*512 + n))*32 + kg*8);
        f32x4 aq = __builtin_amdgcn_mfma_f32_16x16x32_f16(a, bf, (f32x4){0.f,0.f,0.f,0.f}, 0,0,0);
        #pragma unroll
        for (int rr=0;rr<4;rr++)
          qs[(kg*4+rr)*512 + n] = aq[rr];
      }
    }
    __syncthreads();
    // publish qp (wide sc1): 2048 x 16B
    {
      #pragma unroll
      for (int p=0;p<4;p++){
        int cid = p*512 + tid;
        u32x4 v = *(const u32x4*)(ybuf + cid*16);
        st16_sc1(qpg + (size_t)blk*32768 + cid*16, v);
      }
    }
    cbar(flags, cbase, r, tid, 2*t+1);

    // ---------- F: gather own batch's 16 q-partials, sum ----------
    {
      u32x4 gq[4];
      #pragma unroll
      for (int p=0;p<4;p++){
        int cid = p*512 + tid, s = cid>>7, off = cid&127;
        ld16_sc1(qpg + (size_t)(cbase+s)*32768 + r*2048 + off*16, gq[p]);
      }
      vwait();
      #pragma unroll
      for (int p=0;p<4;p++){
        int cid = p*512 + tid;
        *(u32x4*)(ybuf + cid*16) = gq[p];
      }
      __syncthreads();
      const float* qin = (const float*)ybuf;
      float qsum = 0.f;
      #pragma unroll
      for (int s=0;s<16;s++) qsum += qin[s*512 + tid];
      q_l[tid] = qsum;
    }
    __syncthreads();

    // ---------- G: scores -> softmax -> ctx ----------
    for (int i = wave; i < 60; i += 8){
      const f16* krow = keys16 + ((size_t)(bown*60+i))*512;
      float p = 0.f;
      #pragma unroll
      for (int s=0;s<8;s++){
        int u = lane + s*64;
        p += tanh_fast((float)krow[u] + q_l[u]) * v_l[u];
      }
      #pragma unroll
      for (int m=32;m;m>>=1) p += __shfl_xor(p, m, 64);
      if (lane == 0) sc_l[i] = p;
    }
    __syncthreads();
    if (wave == 0){
      float s = (lane < 60) ? sc_l[lane] : -1e30f;
      float mx = s;
      #pragma unroll
      for (int m=32;m;m>>=1) mx = fmaxf(mx, __shfl_xor(mx, m, 64));
      float ev = (lane < 60) ? __expf(s - mx) : 0.f;
      float sum = ev;
      #pragma unroll
      for (int m=32;m;m>>=1) sum += __shfl_xor(sum, m, 64);
      if (lane < 60) sc_l[lane] = ev / sum;
    }
    __syncthreads();
    {
      float cx = 0.f;
      #pragma unroll
      for (int i=0;i<60;i++) cx += sc_l[i] * (float)mem_lds[i*512 + tid];
      cx16_l[tid] = (f16)cx;
    }
    __syncthreads();
    if (tid < 64){
      u32x4 v = *(const u32x4*)((const char*)cx16_l + tid*16);
      st16_sc1(yt + (size_t)bown*2048 + 1024 + tid*16, v);
    }
    cbar(flags, cbase, r, tid, 2*t+2);
  }
}

// ---------------- host ----------------
extern "C" void kernel_launch(void* const* d_in, const int* in_sizes, int n_in,
                              void* d_out, int out_size, void* d_ws, size_t ws_size,
                              hipStream_t stream)
{
  const int*   dec  = (const int*)  d_in[0];
  const float* h0   = (const float*)d_in[1];
  const float* c0   = (const float*)d_in[2];
  const float* mem  = (const float*)d_in[3];
  const float* embt = (const float*)d_in[4];
  const float* Wk   = (const float*)d_in[5];
  const float* Uk   = (const float*)d_in[6];
  const float* bk   = (const float*)d_in[7];
  const float* Wm   = (const float*)d_in[8];
  const float* Wq   = (const float*)d_in[9];
  const float* va   = (const float*)d_in[10];
  const float* Wa   = (const float*)d_in[11];
  const float* Wfc  = (const float*)d_in[12];
  const float* bfc  = (const float*)d_in[13];
  char* ws = (char*)d_ws;

  hipMemsetAsync(ws + OFF_SYNC, 0, 8192, stream);

  prep_elem<<<4096, 256, 0, stream>>>(ws, dec, h0, mem, embt, Wa, bk);
  prep_swz <<<464, 256, 0, stream>>>(ws, Wm, Wk, Uk, Wa, Wq);
  prep_wfc <<<dim3(133,16), 256, 0, stream>>>(ws, Wfc);

  // keys = memory @ Wm : [3840,512] f16
  gemm16<128,64,2,2,1><<<dim3(8,30), 256, 0, stream>>>(
      (const f16*)(ws+OFF_MEM16), 512, (const f16*)(ws+OFF_WMSWZ), 512,
      ws+OFF_KEYS, nullptr, 3840, 512, 3840, 512);
  // embW = embA @ WkTop + bk_perm : [1984,2048] f32 (perm cols)
  gemm16<128,64,2,2,0><<<dim3(32,16), 256, 0, stream>>>(
      (const f16*)(ws+OFF_EMBA), 320, (const f16*)(ws+OFF_WKTOP), 2048,
      ws+OFF_EMBW, (const float*)(ws+OFF_BKP), 1984, 320, 1984, 2048);
  // Wca = Wa @ WkAttn : [1024,2048] f32 (perm cols)
  gemm16<128,64,2,2,0><<<dim3(32,8), 256, 0, stream>>>(
      (const f16*)(ws+OFF_WA16), 512, (const f16*)(ws+OFF_WKATT), 2048,
      ws+OFF_WCA, nullptr, 1024, 512, 1024, 2048);
  build_wstar<<<256, 256, 0, stream>>>(ws, Uk);

  recur<<<64, 512, 0, stream>>>(ws, c0, va);

  // attn_all = Y @ Wa : [1984,512] f16
  gemm16<128,64,2,2,1><<<dim3(8,16), 256, 0, stream>>>(
      (const f16*)(ws+OFF_YALL), 1024, (const f16*)(ws+OFF_WASWZ), 512,
      ws+OFF_ATT16, nullptr, 1984, 1024, 1984, 512);
  // logits = attn_all @ Wfc + bfc -> d_out [b][t][vocab]  (BM=256 halves Wfc re-reads)
  gemm16<256,128,4,2,2><<<dim3(266,8), 512, 0, stream>>>(
      (const f16*)(ws+OFF_ATT16), 512, (const f16*)(ws+OFF_WFC), VOCP,
      d_out, bfc, 1984, 512, 1984, VOC);
}